// Round 7
// baseline (340.930 us; speedup 1.0000x reference)
//
#include <hip/hip_runtime.h>
#include <stddef.h>

typedef unsigned short u16;
typedef unsigned short u16x8 __attribute__((ext_vector_type(8)));
typedef short s16x8 __attribute__((ext_vector_type(8)));
typedef float f32x4 __attribute__((ext_vector_type(4)));

#define B_ 2
#define T_ 2048
#define E_ 2048
#define H_ 16

__device__ inline float us2f(u16 u){
  unsigned int i = ((unsigned int)u) << 16;
  return __builtin_bit_cast(float, i);
}
__device__ inline u16 f2us(float f){
  unsigned int x = __builtin_bit_cast(unsigned int, f);
  unsigned int r = (x + 0x7fffu + ((x >> 16) & 1u)) >> 16;
  return (u16)r;
}
__device__ inline f32x4 mfma32(s16x8 a, s16x8 b, f32x4 c){
  return __builtin_amdgcn_mfma_f32_16x16x32_bf16(a, b, c, 0, 0, 0);
}
__device__ inline s16x8 ld8(const u16* p){
  return __builtin_bit_cast(s16x8, *(const u16x8*)p);
}
// async global->LDS, 16B per lane; LDS dest = wave-uniform base + lane*16 (m97/m104)
__device__ inline void gload_lds16(const u16* g, u16* l){
  __builtin_amdgcn_global_load_lds(
      (const __attribute__((address_space(1))) unsigned int*)(g),
      (__attribute__((address_space(3))) unsigned int*)(l), 16, 0, 0);
}

// ==== FUSED stage 1: weight prep (transposes + cvt) U input cvt; independent ====
// blocks [0,5696): transposes; [5696,6208): wkvb cvt; [6208,22592): query/key cvt
__global__ __launch_bounds__(256) void prep_cvt(
    const float* __restrict__ wq, const float* __restrict__ wkva,
    const float* __restrict__ wo, const float* __restrict__ wkvb,
    const float* __restrict__ query, const float* __restrict__ key_,
    u16* __restrict__ wqT, u16* __restrict__ wkvaT, u16* __restrict__ woT,
    u16* __restrict__ wkvbB, u16* __restrict__ queryB, u16* __restrict__ keyB)
{
  __shared__ float tile[32][33];
  const int bid = blockIdx.x;
  const int tid = threadIdx.x;
  if (bid < 5696) {
    const float* in; u16* out; int R, C, bx, by;
    if (bid < 3072)      { in = wq;   out = wqT;   R = 2048; C = 1536; bx = bid % 48;          by = bid / 48; }
    else if (bid < 3648) { in = wkva; out = wkvaT; R = 2048; C = 288;  bx = (bid-3072) % 9;    by = (bid-3072) / 9; }
    else                 { in = wo;   out = woT;   R = 1024; C = 2048; bx = (bid-3648) % 64;   by = (bid-3648) / 64; }
    int tx = tid & 31, ty = tid >> 5;   // 32 x 8
    int c0 = bx * 32, r0 = by * 32;
    for (int i = ty; i < 32; i += 8){
      int r = r0 + i, c = c0 + tx;
      tile[i][tx] = (r < R && c < C) ? in[(size_t)r * C + c] : 0.f;
    }
    __syncthreads();
    for (int i = ty; i < 32; i += 8){
      int c = c0 + i, r = r0 + tx;
      if (c < C && r < R) out[(size_t)c * R + r] = f2us(tile[tx][i]);
    }
  } else if (bid < 6208) {
    int i = (bid - 5696) * 1024 + tid * 4;   // 512 blocks x 1024 elems = 2048*256
    f32x4 v = *(const f32x4*)(wkvb + i);
    wkvbB[i]   = f2us(v[0]); wkvbB[i+1] = f2us(v[1]);
    wkvbB[i+2] = f2us(v[2]); wkvbB[i+3] = f2us(v[3]);
  } else {
    const int n_each = 4096 * 2048;
    int idx = (bid - 6208) * 1024 + tid * 4;
    const float* in; u16* out; int i;
    if (idx < n_each){ in = query; out = queryB; i = idx; }
    else             { in = key_;  out = keyB;   i = idx - n_each; }
    if (i + 3 < n_each){
      f32x4 v = *(const f32x4*)(in + i);
      out[i]   = f2us(v[0]); out[i+1] = f2us(v[1]);
      out[i+2] = f2us(v[2]); out[i+3] = f2us(v[3]);
    }
  }
}

// ==== FUSED stage 2: q-proj (split-K=4, 2-phase dbuf, XCD swizzle) U key-proj ====
// Round-10: proj2 cost model = K-steps x HBM-latency / co-resident-blocks (R6: 70.9us
// == sk+bt summed; overlap null because each K-step still absorbs one ~900cyc miss).
// Levers: (a) split-K 2->4 halves nt AND doubles grid (6/CU supplied; LDS 5/CU, regs
// 120<=128 -> 4/CU effective) -> divisor ~4; (b) XCD swizzle makes B-loads ~200cyc L2
// hits (per-XCD WS 3.5MB); (c) bt gets XCD-affine map (2MB keyB panel + 1.2MB wkvaT
// per XCD); (d) setprio around sk MFMA (heterogeneous co-residency = T5 role split).
// blocks [0,1536): sk4; [1536,1856): 64x64 bt.
__global__ __launch_bounds__(256) void proj2(
    const u16* __restrict__ queryB, const u16* __restrict__ wqT, u16* __restrict__ qp,
    const u16* __restrict__ keyB, const u16* __restrict__ wkvaT, u16* __restrict__ kvall)
{
  __shared__ __align__(16) u16 smem[16384];   // sk: As[0..8192) Bs[8192..16384); bt: 5120 used
  const int bid = blockIdx.x;
  const int tid  = threadIdx.x;
  const int lane = tid & 63;
  const int wid  = tid >> 6;
  const int quad = lane >> 4;
  const int col  = lane & 15;

  if (bid < 1536) {
    // ---- split-K=4 2-phase 128x128 GEMM: M=4096 N=1536 K=2048 Klen=512 ----
    const int N = 1536, K = 2048, Klen = 512;
    const int swz = (bid & 7) * 192 + (bid >> 3);
    const int kh  = swz / 384;
    const int rem = swz % 384;
    const int bm = (rem / 12) * 128;
    const int bn = (rem % 12) * 128;
    const int waveM = wid >> 1, waveN = wid & 1;
    u16* As = smem;
    u16* Bs = smem + 8192;

    const int srow = wid * 16 + (lane >> 2);
    const int scol = (lane & 3) * 8;
    const u16* ga = queryB + (size_t)(bm + srow) * K + kh * Klen + scol;
    const u16* gb = wqT    + (size_t)(bn + srow) * K + kh * Klen + scol;
    const size_t rowskip = (size_t)64 * K;
    u16* Cp = qp + (size_t)kh * 4096 * N;

    f32x4 acc[4][4] = {};
    const int nt = Klen >> 5;   // 16

    auto STAGE = [&](int buf, int kk){
      u16* la = &As[buf * 4096 + wid * 512];
      u16* lb = &Bs[buf * 4096 + wid * 512];
      gload_lds16(ga + kk,           la);
      gload_lds16(ga + rowskip + kk, la + 2048);
      gload_lds16(gb + kk,           lb);
      gload_lds16(gb + rowskip + kk, lb + 2048);
    };

    STAGE(0, 0);
    asm volatile("s_waitcnt vmcnt(0)" ::: "memory");
    __builtin_amdgcn_s_barrier();
    __builtin_amdgcn_sched_barrier(0);

    int cur = 0;
    for (int it = 0; it < nt; ++it){
      if (it + 1 < nt) STAGE(cur ^ 1, (it + 1) * 32);
      const u16* as = &As[cur * 4096];
      const u16* bs = &Bs[cur * 4096];
      s16x8 af[4], bf[4];
#pragma unroll
      for (int i = 0; i < 4; ++i) af[i] = ld8(&as[(waveM*64 + i*16 + col) * 32 + quad*8]);
#pragma unroll
      for (int i = 0; i < 4; ++i) bf[i] = ld8(&bs[(waveN*64 + i*16 + col) * 32 + quad*8]);
      __builtin_amdgcn_s_setprio(1);
#pragma unroll
      for (int i = 0; i < 4; ++i)
#pragma unroll
        for (int j = 0; j < 4; ++j)
          acc[i][j] = mfma32(af[i], bf[j], acc[i][j]);
      __builtin_amdgcn_s_setprio(0);
      asm volatile("s_waitcnt lgkmcnt(0)" ::: "memory");
      if (it + 1 < nt)
        asm volatile("s_waitcnt vmcnt(0)" ::: "memory");
      __builtin_amdgcn_s_barrier();
      __builtin_amdgcn_sched_barrier(0);
      cur ^= 1;
    }
#pragma unroll
    for (int i = 0; i < 4; ++i)
#pragma unroll
      for (int j = 0; j < 4; ++j)
#pragma unroll
        for (int r = 0; r < 4; ++r) {
          int row = bm + waveM*64 + i*16 + quad*4 + r;
          int c   = bn + waveN*64 + j*16 + col;
          Cp[(size_t)row * N + c] = f2us(acc[i][j][r]);
        }
  } else {
    // ---- legacy 64x64 GEMM: kvall = keyB @ wkvaT^T, M=4096 N=288 K=2048 ----
    // XCD-affine: xcd = r_&7 (bid%8 == r_%8 since 1536%8==0); byi band of 8 per XCD
    // -> per-XCD WS = 2MB keyB + 1.2MB wkvaT < 4MB L2.
    const int N = 288, K = 2048;
    const int r_ = bid - 1536;          // 320 blocks
    const int g  = r_ >> 3;             // 0..39
    const int bm = ((r_ & 7) * 8 + g / 5) * 64;
    const int bn = (g % 5) * 64;
    const int lr = tid >> 2;
    const int lc = (tid & 3) * 8;
    const int waveM = wid >> 1, waveN = wid & 1;
    u16* As = smem;                    // [64][40]
    u16* Bs = smem + 2560;

    f32x4 acc[2][2];
    for (int i = 0; i < 2; ++i)
      for (int j = 0; j < 2; ++j)
        acc[i][j] = (f32x4){0.f, 0.f, 0.f, 0.f};

    const u16x8 zero8 = {0,0,0,0,0,0,0,0};
    const bool bok = (bn + lr) < N;
    const u16* arow = keyB  + (size_t)(bm + lr) * K + lc;
    const u16* brow = wkvaT + (size_t)(bn + lr) * K + lc;

    for (int kk = 0; kk < K; kk += 32) {
      u16x8 av = *(const u16x8*)(arow + kk);
      u16x8 bv = bok ? *(const u16x8*)(brow + kk) : zero8;
      __syncthreads();
      *(u16x8*)&As[lr*40 + lc] = av;
      *(u16x8*)&Bs[lr*40 + lc] = bv;
      __syncthreads();
      s16x8 af0 = ld8(&As[(waveM*32 + col)*40 + quad*8]);
      s16x8 af1 = ld8(&As[(waveM*32 + 16 + col)*40 + quad*8]);
      s16x8 bf0 = ld8(&Bs[(waveN*32 + col)*40 + quad*8]);
      s16x8 bf1 = ld8(&Bs[(waveN*32 + 16 + col)*40 + quad*8]);
      acc[0][0] = mfma32(af0, bf0, acc[0][0]);
      acc[0][1] = mfma32(af0, bf1, acc[0][1]);
      acc[1][0] = mfma32(af1, bf0, acc[1][0]);
      acc[1][1] = mfma32(af1, bf1, acc[1][1]);
    }
    for (int am = 0; am < 2; ++am)
      for (int bnn = 0; bnn < 2; ++bnn)
        for (int i = 0; i < 4; ++i) {
          int r = bm + waveM*32 + am*16 + quad*4 + i;
          int c = bn + waveN*32 + bnn*16 + col;
          if (c < N) kvall[(size_t)r * N + c] = f2us(acc[am][bnn][i]);
        }
  }
}

// ------- 2-phase double-buffered 128x128 GEMM (T3-minimum, XCD-swizzled) -------
// STAGE(buf^1, t+1) issued BEFORE ds_read+MFMA of buf[cur]; one barrier per K-step;
// vmcnt(0) covers loads issued a full compute-phase earlier (verified R5: sk 45.6 -> <40).
template<int OUT_F32>
__global__ __launch_bounds__(256) void gemm128(const u16* __restrict__ A,
    const u16* __restrict__ Bt, void* __restrict__ Cp, int M, int N, int K, int gx)
{
  __shared__ __align__(16) u16 As[2 * 128 * 32];
  __shared__ __align__(16) u16 Bs[2 * 128 * 32];
  const int lin = blockIdx.x;
  const int cpx = gridDim.x >> 3;
  const int swz = (lin & 7) * cpx + (lin >> 3);
  const int bxi = swz % gx;
  const int byi = swz / gx;
  const int tid  = threadIdx.x;
  const int lane = tid & 63;
  const int wid  = tid >> 6;
  const int quad = lane >> 4;
  const int col  = lane & 15;
  const int bm = byi * 128;
  const int bn = bxi * 128;
  const int waveM = wid >> 1, waveN = wid & 1;

  const int srow = wid * 16 + (lane >> 2);
  const int scol = (lane & 3) * 8;
  const u16* ga = A  + (size_t)(bm + srow) * K + scol;
  const u16* gb = Bt + (size_t)(bn + srow) * K + scol;
  const size_t rowskip = (size_t)64 * K;

  f32x4 acc[4][4] = {};
  const int nt = K >> 5;

  auto STAGE = [&](int buf, int kk){
    u16* la = &As[buf * 4096 + wid * 512];
    u16* lb = &Bs[buf * 4096 + wid * 512];
    gload_lds16(ga + kk,           la);
    gload_lds16(ga + rowskip + kk, la + 2048);
    gload_lds16(gb + kk,           lb);
    gload_lds16(gb + rowskip + kk, lb + 2048);
  };

  STAGE(0, 0);
  asm volatile("s_waitcnt vmcnt(0)" ::: "memory");
  __builtin_amdgcn_s_barrier();
  __builtin_amdgcn_sched_barrier(0);

  int cur = 0;
  for (int it = 0; it < nt; ++it){
    if (it + 1 < nt) STAGE(cur ^ 1, (it + 1) * 32);
    const u16* as = &As[cur * 4096];
    const u16* bs = &Bs[cur * 4096];
    s16x8 af[4], bf[4];
#pragma unroll
    for (int i = 0; i < 4; ++i) af[i] = ld8(&as[(waveM*64 + i*16 + col) * 32 + quad*8]);
#pragma unroll
    for (int i = 0; i < 4; ++i) bf[i] = ld8(&bs[(waveN*64 + i*16 + col) * 32 + quad*8]);
#pragma unroll
    for (int i = 0; i < 4; ++i)
#pragma unroll
      for (int j = 0; j < 4; ++j)
        acc[i][j] = mfma32(af[i], bf[j], acc[i][j]);
    asm volatile("s_waitcnt lgkmcnt(0)" ::: "memory");
    if (it + 1 < nt)
      asm volatile("s_waitcnt vmcnt(0)" ::: "memory");
    __builtin_amdgcn_s_barrier();
    __builtin_amdgcn_sched_barrier(0);
    cur ^= 1;
  }
#pragma unroll
  for (int i = 0; i < 4; ++i)
#pragma unroll
    for (int j = 0; j < 4; ++j)
#pragma unroll
      for (int r = 0; r < 4; ++r) {
        int row = bm + waveM*64 + i*16 + quad*4 + r;
        int c   = bn + waveN*64 + j*16 + col;
        if (OUT_F32) ((float*)Cp)[(size_t)row * N + c] = acc[i][j][r];
        else         ((u16*)Cp)[(size_t)row * N + c]   = f2us(acc[i][j][r]);
      }
}

// ==== FUSED stage 3: qsplit (4 partials) U ln_p2_rope U c2 ====
// blocks [0,3072): qsplit; [3072,7168): ln_p2_rope; [7168,9216): c2
__global__ __launch_bounds__(256) void mid3(
    const u16* __restrict__ qp, const int* __restrict__ pos, u16* __restrict__ qh,
    const u16* __restrict__ kvall, const float* __restrict__ gamma,
    const float* __restrict__ beta, const float* __restrict__ fcpw,
    const float* __restrict__ fcpb, u16* __restrict__ kvn,
    float* __restrict__ P2, u16* __restrict__ kpe,
    const float* __restrict__ fccw, const float* __restrict__ fccb,
    float* __restrict__ C2)
{
  __shared__ float fsm[520];    // ln: kvs[256]+part[256]+redS[4]+redS2[4]; c2: pe+part
  const int bid = blockIdx.x;
  const int tid = threadIdx.x;

  if (bid < 3072) {
    // ---- qsplit: combine 4 split-K partials + rope dims 64..95 ----
    const size_t PS = 4096ull * 1536;
    int idx = bid * 256 + tid;
    int c    = idx % 12;
    int rest = idx / 12;
    int h    = rest & 15;
    int row  = rest >> 4;
    int t    = row & (T_ - 1);
    int b    = row >> 11;
    size_t off = (size_t)row * 1536 + h * 96 + c * 8;
    u16x8 v0 = *(const u16x8*)(qp + off);
    u16x8 v1 = *(const u16x8*)(qp + PS + off);
    u16x8 v2 = *(const u16x8*)(qp + 2*PS + off);
    u16x8 v3 = *(const u16x8*)(qp + 3*PS + off);
    u16x8 v;
    if (c < 8) {
#pragma unroll
      for (int k = 0; k < 8; ++k)
        v[k] = f2us((us2f(v0[k]) + us2f(v1[k])) + (us2f(v2[k]) + us2f(v3[k])));
    } else {
      int i0 = (c - 8) * 4;
      float pp = (float)pos[t];
#pragma unroll
      for (int k = 0; k < 4; ++k){
        int i = i0 + k;
        float ang = pp * __expf((float)(2*i) * -0.28782313657f); // -ln(1e4)/32
        float cs = __cosf(ang), sn = __sinf(ang);
        float xr = (us2f(v0[2*k])   + us2f(v1[2*k]))   + (us2f(v2[2*k])   + us2f(v3[2*k]));
        float xi = (us2f(v0[2*k+1]) + us2f(v1[2*k+1])) + (us2f(v2[2*k+1]) + us2f(v3[2*k+1]));
        v[2*k]   = f2us(xr * cs - xi * sn);
        v[2*k+1] = f2us(xr * sn + xi * cs);
      }
    }
    u16* dst = qh + ((size_t)(b * 16 + h) * T_ + t) * 96;
    *(u16x8*)(dst + c * 8) = v;
  } else if (bid < 7168) {
    // ---- layernorm(kv) + P2 + rope(k_pe) ----
    const int row = bid - 3072;
    const int lane = tid & 63, wid = tid >> 6;
    float* kvs   = fsm;
    float* part  = fsm + 256;
    float* redS  = fsm + 512;
    float* redS2 = fsm + 516;
    const u16* src = kvall + (size_t)row * 288;
    float v = us2f(src[tid]);
    float s1 = v, s2 = v * v;
    for (int off = 1; off < 64; off <<= 1){
      s1 += __shfl_xor(s1, off);
      s2 += __shfl_xor(s2, off);
    }
    if (lane == 0){ redS[wid] = s1; redS2[wid] = s2; }
    __syncthreads();
    float S  = redS[0] + redS[1] + redS[2] + redS[3];
    float Q  = redS2[0] + redS2[1] + redS2[2] + redS2[3];
    float mean = S * (1.f / 256.f);
    float var  = Q * (1.f / 256.f) - mean * mean;
    float rstd = rsqrtf(var + 1e-5f);
    float xn = (v - mean) * rstd * gamma[tid] + beta[tid];
    kvs[tid] = xn;
    kvn[(size_t)row * 256 + tid] = f2us(xn);
    __syncthreads();
    {
      int oc = tid & 63, pp = tid >> 6;
      float acc = 0.f;
#pragma unroll 8
      for (int c = pp * 64; c < pp * 64 + 64; ++c)
        acc += kvs[c] * fcpw[c * 64 + oc];
      part[tid] = acc;
    }
    __syncthreads();
    if (tid < 64) {
      P2[(size_t)row * 64 + tid] = fcpb[tid] + part[tid] + part[64 + tid]
                                 + part[128 + tid] + part[192 + tid];
    } else if (tid < 80) {
      int i = tid - 64;
      int t = row & (T_ - 1);
      float ang = (float)pos[t] * __expf((float)(2*i) * -0.28782313657f);
      float c = __cosf(ang), s = __sinf(ang);
      float xr = us2f(src[256 + 2*i]);
      float xi = us2f(src[257 + 2*i]);
      kpe[(size_t)row * 32 + 2*i]     = f2us(xr * c - xi * s);
      kpe[(size_t)row * 32 + 2*i + 1] = f2us(xr * s + xi * c);
    }
  } else {
    // ---- C2[t] = sinusoid_pe(t/2) @ fc_c_w + b ----
    const int t = bid - 7168;
    float* pe   = fsm;
    float* part = fsm + 256;
    float p = (float)(t >> 1);
    if (tid < 128){
      float div = __expf((float)(2*tid) * -0.03597789207f);  // -ln(1e4)/256
      float a = p * div;
      pe[2*tid]   = __sinf(a);
      pe[2*tid+1] = __cosf(a);
    }
    __syncthreads();
    {
      int oc = tid & 63, pp = tid >> 6;
      float acc = 0.f;
#pragma unroll 8
      for (int c = pp * 64; c < pp * 64 + 64; ++c)
        acc += pe[c] * fccw[c * 64 + oc];
      part[tid] = acc;
    }
    __syncthreads();
    if (tid < 64)
      C2[t * 64 + tid] = fccb[tid] + part[tid] + part[64 + tid]
                       + part[128 + tid] + part[192 + tid];
  }
}

// ---------------- kv_t: block-diag (DR=2) temporal conv; 4 rows/block --------
__global__ __launch_bounds__(256) void kvt_kernel(const float* __restrict__ C2,
    const float* __restrict__ P2, const u16* __restrict__ kvn, u16* __restrict__ kvt)
{
  const int row = blockIdx.x * 4 + (threadIdx.x >> 6);   // 1024 blocks x 4 waves
  const int lane = threadIdx.x & 63;
  const int t = row & (T_ - 1);
  float c2v = C2[t * 64 + lane];
  float da = c2v * P2[(size_t)row * 64 + lane];
  for (int off = 1; off < 64; off <<= 1) da += __shfl_xor(da, off);
  float wtt = 1.f / (1.f + __expf(-da));
  const bool odd = (t & 1);
  float wts = 0.f;
  if (odd){
    float db = c2v * P2[(size_t)(row - 1) * 64 + lane];
    for (int off = 1; off < 64; off <<= 1) db += __shfl_xor(db, off);
    wts = 1.f / (1.f + __expf(-db));
  }
  for (int c = lane; c < 256; c += 64){
    float val = wtt * us2f(kvn[(size_t)row * 256 + c]);
    if (odd) val += wts * us2f(kvn[(size_t)(row - 1) * 256 + c]);
    kvt[(size_t)row * 256 + c] = f2us(val);
  }
}

// ---- fused: Vt transpose-gather (blocks 0..511) + Kc gather (blocks 512..2047) ----
// Kc is stored XOR-SWIZZLED within each 64-key tile: logical 16B chunk c (0..11)
// of local key kl lands at c' = (c&12) | ((c&3) ^ ((kl>>1)&3)).  attn_kernel
// stages tiles linearly via global_load_lds and applies the same XOR on ds_read,
// making the QK B-operand reads LDS bank-conflict-free (was 4-way).
__global__ __launch_bounds__(256) void vtkc_kernel(const u16* __restrict__ kvb,
    const u16* __restrict__ kpe, u16* __restrict__ Vt, u16* __restrict__ Kc)
{
  __shared__ __align__(16) u16 tile[64][72];
  const int tid = threadIdx.x;
  if (blockIdx.x < 512) {
    const int bid = blockIdx.x;
    const int jt = bid & 15;
    const int h  = (bid >> 4) & 15;
    const int b  = bid >> 8;
    const int jl = tid >> 2;
    const int dseg = (tid & 3) * 16;
    const int j0 = jt * 64;
    {
      int s_ = 2 * (j0 + jl) + 1;
      const u16* src = kvb + ((size_t)(b * T_ + s_)) * 2048 + h * 128 + 64 + dseg;
      *(u16x8*)&tile[jl][dseg]     = *(const u16x8*)(src);
      *(u16x8*)&tile[jl][dseg + 8] = *(const u16x8*)(src + 8);
    }
    __syncthreads();
    const int dl = tid >> 2;
    const int jseg = (tid & 3) * 16;
    u16* dst = Vt + ((size_t)(b * 16 + h) * 64 + dl) * 1024 + j0 + jseg;
    u16x8 o;
    for (int r = 0; r < 8; ++r) o[r] = tile[jseg + r][dl];
    *(u16x8*)dst = o;
    for (int r = 0; r < 8; ++r) o[r] = tile[jseg + 8 + r][dl];
    *(u16x8*)(dst + 8) = o;
  } else {
    int idx = (blockIdx.x - 512) * 256 + tid;   // 1536 blocks x 256 chunks
    int c  = idx % 12;
    int j  = (idx / 12) & 1023;
    int bh = idx / (12 * 1024);
    if (bh >= B_ * H_) return;
    int b = bh >> 4, h = bh & 15;
    int t = 2 * j + 1;
    u16x8 v;
    if (c < 8) v = *(const u16x8*)(kvb + ((size_t)(b * T_ + t)) * 2048 + h * 128 + c * 8);
    else       v = *(const u16x8*)(kpe + ((size_t)(b * T_ + t)) * 32 + (c - 8) * 8);
    int kl = j & 63;                              // local key within 64-key tile
    int cs = (c & 12) | ((c & 3) ^ ((kl >> 1) & 3));   // swizzled chunk slot
    *(u16x8*)(Kc + ((size_t)bh * 1024 + j) * 96 + cs * 8) = v;
  }
}

// ---- flash attention: fixed-max softmax, 64-key LDS chunks, one q-tile/block ----
// 1024 blocks (one qt each, big-qt first), 30KB LDS -> 16 waves/CU.
// Ks reads XOR-deswizzled (conflict-free).
__global__ __launch_bounds__(256) void attn_kernel(
    const u16* __restrict__ qh, const u16* __restrict__ kvb,
    const u16* __restrict__ kpe, const u16* __restrict__ Kc,
    const u16* __restrict__ Vt, u16* __restrict__ xout)
{
  __shared__ __align__(16) u16 Ks[64 * 96];        // 64 keys x 96 dims, swizzled
  __shared__ __align__(16) u16 Vs[64][72];         // 64 dims x 64 keys (+8 pad)
  __shared__ __align__(16) u16 pbufA[4][16 * 72];  // per-wave P: 16 q x 64 keys
  const int tid  = threadIdx.x;
  const int wid  = tid >> 6;
  const int lane = tid & 63;
  const int quad = lane >> 4;
  const int col  = lane & 15;
  const int qt   = 31 - (blockIdx.x >> 5);   // big q-tiles dispatched first
  const int bh   = blockIdx.x & 31;
  const int b    = bh >> 4;
  const int h    = bh & 15;
  u16* pbuf = pbufA[wid];
  const float scale = 0.10206207262f;   // 96^-0.5
  const u16* KcH = Kc + (size_t)bh * 1024 * 96;
  const u16* VtH = Vt + (size_t)bh * 64 * 1024;
  const int t0 = qt * 64 + wid * 16;
  const int qo = (quad * 8) ^ (((col >> 1) & 3) << 3);   // deswizzled read offset

  s16x8 aq0, aq1, aq2;
  {
    const u16* qrow = qh + ((size_t)bh * T_ + t0 + col) * 96;
    aq0 = ld8(qrow + quad * 8);
    aq1 = ld8(qrow + 32 + quad * 8);
    aq2 = ld8(qrow + 64 + quad * 8);
  }
  float sself;
  {
    const int t = t0 + col;
    const u16* qrow = qh + ((size_t)bh * T_ + t) * 96;
    const u16* ka = kvb + ((size_t)(b * T_ + t)) * 2048 + h * 128;
    const u16* kp = kpe + ((size_t)(b * T_ + t)) * 32;
    float a = 0.f;
#pragma unroll
    for (int c = 0; c < 8; ++c){
      u16x8 qv = *(const u16x8*)(qrow + c * 8);
      u16x8 kv = *(const u16x8*)(ka + c * 8);
#pragma unroll
      for (int jj = 0; jj < 8; ++jj) a += us2f(qv[jj]) * us2f(kv[jj]);
    }
#pragma unroll
    for (int c = 0; c < 4; ++c){
      u16x8 qv = *(const u16x8*)(qrow + 64 + c * 8);
      u16x8 kv = *(const u16x8*)(kp + c * 8);
#pragma unroll
      for (int jj = 0; jj < 8; ++jj) a += us2f(qv[jj]) * us2f(kv[jj]);
    }
    sself = a * scale;
  }
  float es[4], lacc[4];
  f32x4 O[4];
#pragma unroll
  for (int i = 0; i < 4; ++i){
    es[i] = __expf(__shfl(sself, quad * 4 + i));
    lacc[i] = 0.f;
  }
#pragma unroll
  for (int nt = 0; nt < 4; ++nt)
#pragma unroll
    for (int i = 0; i < 4; ++i){
      int t = t0 + quad * 4 + i;
      O[nt][i] = es[i] * us2f(kvb[((size_t)(b * T_ + t)) * 2048 + h * 128 + 64 + nt * 16 + col]);
    }

  const int nb = (qt * 32 + 94) >> 6;   // 64-key chunks, block-uniform
  for (int blk = 0; blk < nb; ++blk) {
    const int jb = blk * 64;
    __syncthreads();
    {
      // K tile: 12KB contiguous (pre-swizzled in global), linear async stage
      const u16* gk = KcH + (size_t)jb * 96 + (wid * 3) * 512 + lane * 8;
      u16* lk = &Ks[(wid * 3) * 512];
#pragma unroll
      for (int k = 0; k < 3; ++k)
        gload_lds16(gk + k * 512, lk + k * 512);
      // V tile: 64 dims x 64 keys, reg-staged into padded rows
      int d = tid >> 2, c4 = tid & 3;
      const u16* gv = VtH + (size_t)d * 1024 + jb + c4 * 16;
      u16* lv = &Vs[d][c4 * 16];
      *(u16x8*)(lv)     = *(const u16x8*)(gv);
      *(u16x8*)(lv + 8) = *(const u16x8*)(gv + 8);
    }
    __syncthreads();
#pragma unroll
    for (int cc = 0; cc < 2; ++cc){
      const u16* k0 = &Ks[(cc * 32 + col) * 96];
      const u16* k1 = k0 + 16 * 96;
      f32x4 s0 = {0,0,0,0}, s1 = {0,0,0,0};
      s0 = mfma32(aq0, ld8(k0 + qo), s0);
      s0 = mfma32(aq1, ld8(k0 + 32 + qo), s0);
      s0 = mfma32(aq2, ld8(k0 + 64 + qo), s0);
      s1 = mfma32(aq0, ld8(k1 + qo), s1);
      s1 = mfma32(aq1, ld8(k1 + 32 + qo), s1);
      s1 = mfma32(aq2, ld8(k1 + 64 + qo), s1);
      int key0 = jb + cc * 32 + col;
#pragma unroll
      for (int i = 0; i < 4; ++i){
        int lim = (t0 + quad * 4 + i) >> 1;
        float p0 = (key0 < lim)      ? __expf(s0[i] * scale) : 0.f;
        float p1 = (key0 + 16 < lim) ? __expf(s1[i] * scale) : 0.f;
        lacc[i] += p0 + p1;
        pbuf[(quad * 4 + i) * 72 + cc * 32 + col]      = f2us(p0);
        pbuf[(quad * 4 + i) * 72 + cc * 32 + 16 + col] = f2us(p1);
      }
    }
    asm volatile("s_waitcnt lgkmcnt(0)" ::: "memory");
    __builtin_amdgcn_sched_barrier(0);
#pragma unroll
    for (int cc = 0; cc < 2; ++cc){
      s16x8 pf = ld8(&pbuf[col * 72 + cc * 32 + quad * 8]);
#pragma unroll
      for (int nt = 0; nt < 4; ++nt)
        O[nt] = mfma32(pf, ld8(&Vs[nt * 16 + col][cc * 32 + quad * 8]), O[nt]);
    }
  }
#pragma unroll
  for (int i = 0; i < 4; ++i){
    float l = lacc[i];
    l += __shfl_xor(l, 1);
    l += __shfl_xor(l, 2);
    l += __shfl_xor(l, 4);
    l += __shfl_xor(l, 8);
    lacc[i] = es[i] + l;
  }
#pragma unroll
  for (int nt = 0; nt < 4; ++nt)
#pragma unroll
    for (int i = 0; i < 4; ++i){
      int t = t0 + quad * 4 + i;
      xout[((size_t)(b * T_ + t)) * 1024 + h * 64 + nt * 16 + col] = f2us(O[nt][i] / lacc[i]);
    }
}

extern "C" void kernel_launch(void* const* d_in, const int* in_sizes, int n_in,
                              void* d_out, int out_size, void* d_ws, size_t ws_size,
                              hipStream_t stream)
{
  (void)in_sizes; (void)n_in; (void)out_size; (void)ws_size;
  const float* query = (const float*)d_in[0];
  const float* key_  = (const float*)d_in[1];
  const int*   pos   = (const int*)d_in[3];
  const float* wq    = (const float*)d_in[4];
  const float* wkva  = (const float*)d_in[5];
  const float* gamma = (const float*)d_in[6];
  const float* beta  = (const float*)d_in[7];
  const float* wkvb  = (const float*)d_in[8];
  const float* wo    = (const float*)d_in[9];
  const float* fccw  = (const float*)d_in[10];
  const float* fccb  = (const float*)d_in[11];
  const float* fcpw  = (const float*)d_in[12];
  const float* fcpb  = (const float*)d_in[13];

  char* p = (char*)d_ws;
  auto alloc = [&](size_t bytes) -> void* {
    void* r = (void*)p;
    p += (bytes + 255) & ~(size_t)255;
    return r;
  };
  u16* wqT    = (u16*)alloc(1536ull * 2048 * 2);
  u16* wkvaT  = (u16*)alloc(288ull  * 2048 * 2);
  u16* woT    = (u16*)alloc(2048ull * 1024 * 2);
  u16* wkvbB  = (u16*)alloc(2048ull * 256 * 2);
  u16* queryB = (u16*)alloc(4096ull * 2048 * 2);
  u16* keyB   = (u16*)alloc(4096ull * 2048 * 2);
  u16* qp     = (u16*)alloc(4ull * 4096 * 1536 * 2);  // 4 split-K partials (50.3MB)
  u16* qh     = (u16*)alloc(65536ull * 96 * 2);    // (B,H,T,96)
  u16* kvall  = (u16*)alloc(4096ull * 288 * 2);
  u16* kvn    = (u16*)alloc(4096ull * 256 * 2);
  u16* kpe    = (u16*)alloc(4096ull * 32 * 2);
  float* P2   = (float*)alloc(4096ull * 64 * 4);
  float* C2   = (float*)alloc(2048ull * 64 * 4);
  u16* kvt    = (u16*)alloc(4096ull * 256 * 2);
  u16* kvb    = (u16*)alloc(4096ull * 2048 * 2);   // per-head [k_abs(64)|v(64)]
  // qp is dead after mid3; Kc/Vt/x are born at vtkc/attn -> alias onto qp
  char* q8 = (char*)qp;
  u16* Kc = (u16*)q8;                                    // 6.29MB (B,H,1024,96)
  u16* Vt = (u16*)(q8 + ((32ull*1024*96*2 + 255) & ~255ull));      // 4.19MB
  u16* x  = (u16*)(q8 + ((32ull*1024*96*2 + 255) & ~255ull)
                      + ((2048ull*1024*2   + 255) & ~255ull));     // 8.39MB

  prep_cvt<<<22592, 256, 0, stream>>>(wq, wkva, wo, wkvb, query, key_,
                                      wqT, wkvaT, woT, wkvbB, queryB, keyB);
  proj2<<<1856, 256, 0, stream>>>(queryB, wqT, qp, keyB, wkvaT, kvall);
  mid3<<<9216, 256, 0, stream>>>(qp, pos, qh, kvall, gamma, beta, fcpw, fcpb,
                                 kvn, P2, kpe, fccw, fccb, C2);
  kvt_kernel<<<1024, 256, 0, stream>>>(C2, P2, kvn, kvt);

  gemm128<0><<<512, 256, 0, stream>>>(kvt, wkvbB, kvb, 4096, 2048, 256, 16);
  vtkc_kernel<<<2048, 256, 0, stream>>>(kvb, kpe, Vt, Kc);
  attn_kernel<<<1024, 256, 0, stream>>>(qh, kvb, kpe, Kc, Vt, x);

  gemm128<1><<<512, 256, 0, stream>>>(x, woT, d_out, 4096, 2048, 1024, 16);
}

// Round 8
// 332.504 us; speedup vs baseline: 1.0253x; 1.0253x over previous
//
#include <hip/hip_runtime.h>
#include <stddef.h>

typedef unsigned short u16;
typedef unsigned short u16x8 __attribute__((ext_vector_type(8)));
typedef short s16x8 __attribute__((ext_vector_type(8)));
typedef float f32x4 __attribute__((ext_vector_type(4)));

#define B_ 2
#define T_ 2048
#define E_ 2048
#define H_ 16

__device__ inline float us2f(u16 u){
  unsigned int i = ((unsigned int)u) << 16;
  return __builtin_bit_cast(float, i);
}
__device__ inline u16 f2us(float f){
  unsigned int x = __builtin_bit_cast(unsigned int, f);
  unsigned int r = (x + 0x7fffu + ((x >> 16) & 1u)) >> 16;
  return (u16)r;
}
__device__ inline f32x4 mfma32(s16x8 a, s16x8 b, f32x4 c){
  return __builtin_amdgcn_mfma_f32_16x16x32_bf16(a, b, c, 0, 0, 0);
}
__device__ inline s16x8 ld8(const u16* p){
  return __builtin_bit_cast(s16x8, *(const u16x8*)p);
}
// async global->LDS, 16B per lane; LDS dest = wave-uniform base + lane*16 (m97/m104)
__device__ inline void gload_lds16(const u16* g, u16* l){
  __builtin_amdgcn_global_load_lds(
      (const __attribute__((address_space(1))) unsigned int*)(g),
      (__attribute__((address_space(3))) unsigned int*)(l), 16, 0, 0);
}

// ==== FUSED stage 1: weight prep (transposes + cvt) U input cvt; independent ====
// blocks [0,5696): transposes; [5696,6208): wkvb cvt; [6208,22592): query/key cvt
__global__ __launch_bounds__(256) void prep_cvt(
    const float* __restrict__ wq, const float* __restrict__ wkva,
    const float* __restrict__ wo, const float* __restrict__ wkvb,
    const float* __restrict__ query, const float* __restrict__ key_,
    u16* __restrict__ wqT, u16* __restrict__ wkvaT, u16* __restrict__ woT,
    u16* __restrict__ wkvbB, u16* __restrict__ queryB, u16* __restrict__ keyB)
{
  __shared__ float tile[32][33];
  const int bid = blockIdx.x;
  const int tid = threadIdx.x;
  if (bid < 5696) {
    const float* in; u16* out; int R, C, bx, by;
    if (bid < 3072)      { in = wq;   out = wqT;   R = 2048; C = 1536; bx = bid % 48;          by = bid / 48; }
    else if (bid < 3648) { in = wkva; out = wkvaT; R = 2048; C = 288;  bx = (bid-3072) % 9;    by = (bid-3072) / 9; }
    else                 { in = wo;   out = woT;   R = 1024; C = 2048; bx = (bid-3648) % 64;   by = (bid-3648) / 64; }
    int tx = tid & 31, ty = tid >> 5;   // 32 x 8
    int c0 = bx * 32, r0 = by * 32;
    for (int i = ty; i < 32; i += 8){
      int r = r0 + i, c = c0 + tx;
      tile[i][tx] = (r < R && c < C) ? in[(size_t)r * C + c] : 0.f;
    }
    __syncthreads();
    for (int i = ty; i < 32; i += 8){
      int c = c0 + i, r = r0 + tx;
      if (c < C && r < R) out[(size_t)c * R + r] = f2us(tile[tx][i]);
    }
  } else if (bid < 6208) {
    int i = (bid - 5696) * 1024 + tid * 4;   // 512 blocks x 1024 elems = 2048*256
    f32x4 v = *(const f32x4*)(wkvb + i);
    wkvbB[i]   = f2us(v[0]); wkvbB[i+1] = f2us(v[1]);
    wkvbB[i+2] = f2us(v[2]); wkvbB[i+3] = f2us(v[3]);
  } else {
    const int n_each = 4096 * 2048;
    int idx = (bid - 6208) * 1024 + tid * 4;
    const float* in; u16* out; int i;
    if (idx < n_each){ in = query; out = queryB; i = idx; }
    else             { in = key_;  out = keyB;   i = idx - n_each; }
    if (i + 3 < n_each){
      f32x4 v = *(const f32x4*)(in + i);
      out[i]   = f2us(v[0]); out[i+1] = f2us(v[1]);
      out[i+2] = f2us(v[2]); out[i+3] = f2us(v[3]);
    }
  }
}

// ==== FUSED stage 2, round-11: INTERLEAVED q-proj U key-proj ====
// R6/R7 lesson: concatenated roles serialize (in-order dispatch fills all CUs with
// sk first; bt runs as a near-idle tail, proj2 == sk+bt summed).  Fix: interleave
// roles in bid-space.  2048 blocks in 256 groups of 8; per 8 groups 3 are sk (768)
// and 5 are bt (1280) -> both roles resident from t=0; bt hides under sk stalls.
// Within each role, bid&7 = XCD and a per-XCD contiguous index keeps L2 locality
// (sk: 4bm x 12bn chunks ~4.1MB; bt: half-kh ~2.4MB).
// sk: split-K=2, 2-phase dbuf (R5-verified), Klen=1024 -> bf16 partials qp[2].
// bt: split-K=4, reg-prefetch (issue next loads after LDS write -> compute-phase
// of latency cover), Klen=512 -> f32 partials kvp[4] (summed in mid3's LN).
__global__ __launch_bounds__(256) void proj2(
    const u16* __restrict__ queryB, const u16* __restrict__ wqT, u16* __restrict__ qp,
    const u16* __restrict__ keyB, const u16* __restrict__ wkvaT, float* __restrict__ kvp)
{
  __shared__ __align__(16) u16 smem[16384];   // sk: As[0..8192) Bs[8192..16384); bt: 5120 used
  const int bid = blockIdx.x;
  const int tid  = threadIdx.x;
  const int lane = tid & 63;
  const int wid  = tid >> 6;
  const int quad = lane >> 4;
  const int col  = lane & 15;
  const int g  = bid >> 3;
  const int e  = bid & 7;      // XCD (round-robin assumption)
  const int gm = g & 7;

  if (gm < 3) {
    // ---- sk: split-K=2 2-phase 128x128 GEMM: M=4096 N=1536 K=2048 Klen=1024 ----
    const int id = e * 96 + (g >> 3) * 3 + gm;     // 0..767, per-XCD contiguous
    const int kh   = id / 384;
    const int r2   = id % 384;
    const int bmHi = r2 / 48;
    const int r3   = r2 % 48;
    const int bn = (r3 >> 2) * 128;
    const int bm = (bmHi * 4 + (r3 & 3)) * 128;
    const int N = 1536, K = 2048, Klen = 1024;
    const int waveM = wid >> 1, waveN = wid & 1;
    u16* As = smem;
    u16* Bs = smem + 8192;

    const int srow = wid * 16 + (lane >> 2);
    const int scol = (lane & 3) * 8;
    const u16* ga = queryB + (size_t)(bm + srow) * K + kh * Klen + scol;
    const u16* gb = wqT    + (size_t)(bn + srow) * K + kh * Klen + scol;
    const size_t rowskip = (size_t)64 * K;
    u16* Cp = qp + (size_t)kh * 4096 * N;

    f32x4 acc[4][4] = {};
    const int nt = Klen >> 5;   // 32

    auto STAGE = [&](int buf, int kk){
      u16* la = &As[buf * 4096 + wid * 512];
      u16* lb = &Bs[buf * 4096 + wid * 512];
      gload_lds16(ga + kk,           la);
      gload_lds16(ga + rowskip + kk, la + 2048);
      gload_lds16(gb + kk,           lb);
      gload_lds16(gb + rowskip + kk, lb + 2048);
    };

    STAGE(0, 0);
    asm volatile("s_waitcnt vmcnt(0)" ::: "memory");
    __builtin_amdgcn_s_barrier();
    __builtin_amdgcn_sched_barrier(0);

    int cur = 0;
    for (int it = 0; it < nt; ++it){
      if (it + 1 < nt) STAGE(cur ^ 1, (it + 1) * 32);
      const u16* as = &As[cur * 4096];
      const u16* bs = &Bs[cur * 4096];
      s16x8 af[4], bf[4];
#pragma unroll
      for (int i = 0; i < 4; ++i) af[i] = ld8(&as[(waveM*64 + i*16 + col) * 32 + quad*8]);
#pragma unroll
      for (int i = 0; i < 4; ++i) bf[i] = ld8(&bs[(waveN*64 + i*16 + col) * 32 + quad*8]);
      __builtin_amdgcn_s_setprio(1);
#pragma unroll
      for (int i = 0; i < 4; ++i)
#pragma unroll
        for (int j = 0; j < 4; ++j)
          acc[i][j] = mfma32(af[i], bf[j], acc[i][j]);
      __builtin_amdgcn_s_setprio(0);
      asm volatile("s_waitcnt lgkmcnt(0)" ::: "memory");
      if (it + 1 < nt)
        asm volatile("s_waitcnt vmcnt(0)" ::: "memory");
      __builtin_amdgcn_s_barrier();
      __builtin_amdgcn_sched_barrier(0);
      cur ^= 1;
    }
#pragma unroll
    for (int i = 0; i < 4; ++i)
#pragma unroll
      for (int j = 0; j < 4; ++j)
#pragma unroll
        for (int r = 0; r < 4; ++r) {
          int row = bm + waveM*64 + i*16 + quad*4 + r;
          int c   = bn + waveN*64 + j*16 + col;
          Cp[(size_t)row * N + c] = f2us(acc[i][j][r]);
        }
  } else {
    // ---- bt: split-K=4 reg-prefetch 64x64 GEMM: kvp[kh] = keyB@wkvaT^T slice ----
    const int id = e * 160 + (g >> 3) * 5 + (gm - 3);   // 0..1279, per-XCD contiguous
    const int kh = id / 320;
    const int r  = id % 320;
    const int bm = (r / 5) * 64;
    const int bn = (r % 5) * 64;
    const int N = 288, K = 2048, Klen = 512;
    const int lr = tid >> 2;
    const int lc = (tid & 3) * 8;
    const int waveM = wid >> 1, waveN = wid & 1;
    u16* As = smem;                    // [64][40] padded (conflict-free ds_read)
    u16* Bs = smem + 2560;

    f32x4 acc[2][2];
    for (int i = 0; i < 2; ++i)
      for (int j = 0; j < 2; ++j)
        acc[i][j] = (f32x4){0.f, 0.f, 0.f, 0.f};

    const u16x8 zero8 = {0,0,0,0,0,0,0,0};
    const bool bok = (bn + lr) < N;
    const u16* arow = keyB  + (size_t)(bm + lr) * K + kh * Klen + lc;
    const u16* brow = wkvaT + (size_t)(bn + lr) * K + kh * Klen + lc;
    float* Cp = kvp + (size_t)kh * 4096 * N;

    u16x8 av = *(const u16x8*)(arow);
    u16x8 bv = bok ? *(const u16x8*)(brow) : zero8;
    for (int kk = 0; kk < Klen; kk += 32) {
      __syncthreads();
      *(u16x8*)&As[lr*40 + lc] = av;
      *(u16x8*)&Bs[lr*40 + lc] = bv;
      if (kk + 32 < Klen){                       // issue next-step loads now;
        av = *(const u16x8*)(arow + kk + 32);    // ds_read+MFMA below covers latency
        bv = bok ? *(const u16x8*)(brow + kk + 32) : zero8;
      }
      __syncthreads();
      s16x8 af0 = ld8(&As[(waveM*32 + col)*40 + quad*8]);
      s16x8 af1 = ld8(&As[(waveM*32 + 16 + col)*40 + quad*8]);
      s16x8 bf0 = ld8(&Bs[(waveN*32 + col)*40 + quad*8]);
      s16x8 bf1 = ld8(&Bs[(waveN*32 + 16 + col)*40 + quad*8]);
      acc[0][0] = mfma32(af0, bf0, acc[0][0]);
      acc[0][1] = mfma32(af0, bf1, acc[0][1]);
      acc[1][0] = mfma32(af1, bf0, acc[1][0]);
      acc[1][1] = mfma32(af1, bf1, acc[1][1]);
    }
    for (int am = 0; am < 2; ++am)
      for (int bnn = 0; bnn < 2; ++bnn)
        for (int i = 0; i < 4; ++i) {
          int rr = bm + waveM*32 + am*16 + quad*4 + i;
          int c  = bn + waveN*32 + bnn*16 + col;
          if (c < N) Cp[(size_t)rr * N + c] = acc[am][bnn][i];
        }
  }
}

// ------- 2-phase double-buffered 128x128 GEMM (T3-minimum, XCD-swizzled) -------
// STAGE(buf^1, t+1) issued BEFORE ds_read+MFMA of buf[cur]; one barrier per K-step;
// vmcnt(0) covers loads issued a full compute-phase earlier (verified R5: sk 45.6 -> <40).
template<int OUT_F32>
__global__ __launch_bounds__(256) void gemm128(const u16* __restrict__ A,
    const u16* __restrict__ Bt, void* __restrict__ Cp, int M, int N, int K, int gx)
{
  __shared__ __align__(16) u16 As[2 * 128 * 32];
  __shared__ __align__(16) u16 Bs[2 * 128 * 32];
  const int lin = blockIdx.x;
  const int cpx = gridDim.x >> 3;
  const int swz = (lin & 7) * cpx + (lin >> 3);
  const int bxi = swz % gx;
  const int byi = swz / gx;
  const int tid  = threadIdx.x;
  const int lane = tid & 63;
  const int wid  = tid >> 6;
  const int quad = lane >> 4;
  const int col  = lane & 15;
  const int bm = byi * 128;
  const int bn = bxi * 128;
  const int waveM = wid >> 1, waveN = wid & 1;

  const int srow = wid * 16 + (lane >> 2);
  const int scol = (lane & 3) * 8;
  const u16* ga = A  + (size_t)(bm + srow) * K + scol;
  const u16* gb = Bt + (size_t)(bn + srow) * K + scol;
  const size_t rowskip = (size_t)64 * K;

  f32x4 acc[4][4] = {};
  const int nt = K >> 5;

  auto STAGE = [&](int buf, int kk){
    u16* la = &As[buf * 4096 + wid * 512];
    u16* lb = &Bs[buf * 4096 + wid * 512];
    gload_lds16(ga + kk,           la);
    gload_lds16(ga + rowskip + kk, la + 2048);
    gload_lds16(gb + kk,           lb);
    gload_lds16(gb + rowskip + kk, lb + 2048);
  };

  STAGE(0, 0);
  asm volatile("s_waitcnt vmcnt(0)" ::: "memory");
  __builtin_amdgcn_s_barrier();
  __builtin_amdgcn_sched_barrier(0);

  int cur = 0;
  for (int it = 0; it < nt; ++it){
    if (it + 1 < nt) STAGE(cur ^ 1, (it + 1) * 32);
    const u16* as = &As[cur * 4096];
    const u16* bs = &Bs[cur * 4096];
    s16x8 af[4], bf[4];
#pragma unroll
    for (int i = 0; i < 4; ++i) af[i] = ld8(&as[(waveM*64 + i*16 + col) * 32 + quad*8]);
#pragma unroll
    for (int i = 0; i < 4; ++i) bf[i] = ld8(&bs[(waveN*64 + i*16 + col) * 32 + quad*8]);
#pragma unroll
    for (int i = 0; i < 4; ++i)
#pragma unroll
      for (int j = 0; j < 4; ++j)
        acc[i][j] = mfma32(af[i], bf[j], acc[i][j]);
    asm volatile("s_waitcnt lgkmcnt(0)" ::: "memory");
    if (it + 1 < nt)
      asm volatile("s_waitcnt vmcnt(0)" ::: "memory");
    __builtin_amdgcn_s_barrier();
    __builtin_amdgcn_sched_barrier(0);
    cur ^= 1;
  }
#pragma unroll
  for (int i = 0; i < 4; ++i)
#pragma unroll
    for (int j = 0; j < 4; ++j)
#pragma unroll
      for (int r = 0; r < 4; ++r) {
        int row = bm + waveM*64 + i*16 + quad*4 + r;
        int c   = bn + waveN*64 + j*16 + col;
        if (OUT_F32) ((float*)Cp)[(size_t)row * N + c] = acc[i][j][r];
        else         ((u16*)Cp)[(size_t)row * N + c]   = f2us(acc[i][j][r]);
      }
}

// ==== FUSED stage 3: qsplit (2 bf16 partials) U ln_p2_rope (4 f32 kvp partials) U c2 ====
// blocks [0,3072): qsplit; [3072,7168): ln_p2_rope; [7168,9216): c2
__global__ __launch_bounds__(256) void mid3(
    const u16* __restrict__ qp, const int* __restrict__ pos, u16* __restrict__ qh,
    const float* __restrict__ kvp, const float* __restrict__ gamma,
    const float* __restrict__ beta, const float* __restrict__ fcpw,
    const float* __restrict__ fcpb, u16* __restrict__ kvn,
    float* __restrict__ P2, u16* __restrict__ kpe,
    const float* __restrict__ fccw, const float* __restrict__ fccb,
    float* __restrict__ C2)
{
  __shared__ float fsm[520];    // ln: kvs[256]+part[256]+redS[4]+redS2[4]; c2: pe+part
  const int bid = blockIdx.x;
  const int tid = threadIdx.x;

  if (bid < 3072) {
    // ---- qsplit: combine 2 split-K partials + rope dims 64..95 ----
    const size_t PS = 4096ull * 1536;
    int idx = bid * 256 + tid;
    int c    = idx % 12;
    int rest = idx / 12;
    int h    = rest & 15;
    int row  = rest >> 4;
    int t    = row & (T_ - 1);
    int b    = row >> 11;
    size_t off = (size_t)row * 1536 + h * 96 + c * 8;
    u16x8 v0 = *(const u16x8*)(qp + off);
    u16x8 v1 = *(const u16x8*)(qp + PS + off);
    u16x8 v;
    if (c < 8) {
#pragma unroll
      for (int k = 0; k < 8; ++k) v[k] = f2us(us2f(v0[k]) + us2f(v1[k]));
    } else {
      int i0 = (c - 8) * 4;
      float pp = (float)pos[t];
#pragma unroll
      for (int k = 0; k < 4; ++k){
        int i = i0 + k;
        float ang = pp * __expf((float)(2*i) * -0.28782313657f); // -ln(1e4)/32
        float cs = __cosf(ang), sn = __sinf(ang);
        float xr = us2f(v0[2*k])   + us2f(v1[2*k]);
        float xi = us2f(v0[2*k+1]) + us2f(v1[2*k+1]);
        v[2*k]   = f2us(xr * cs - xi * sn);
        v[2*k+1] = f2us(xr * sn + xi * cs);
      }
    }
    u16* dst = qh + ((size_t)(b * 16 + h) * T_ + t) * 96;
    *(u16x8*)(dst + c * 8) = v;
  } else if (bid < 7168) {
    // ---- layernorm(sum of 4 kvp partials) + P2 + rope(k_pe) ----
    const int row = bid - 3072;
    const int lane = tid & 63, wid = tid >> 6;
    const size_t PSk = 4096ull * 288;
    float* kvs   = fsm;
    float* part  = fsm + 256;
    float* redS  = fsm + 512;
    float* redS2 = fsm + 516;
    const float* src = kvp + (size_t)row * 288;
    float v = (src[tid] + src[PSk + tid]) + (src[2*PSk + tid] + src[3*PSk + tid]);
    float s1 = v, s2 = v * v;
    for (int off = 1; off < 64; off <<= 1){
      s1 += __shfl_xor(s1, off);
      s2 += __shfl_xor(s2, off);
    }
    if (lane == 0){ redS[wid] = s1; redS2[wid] = s2; }
    __syncthreads();
    float S  = redS[0] + redS[1] + redS[2] + redS[3];
    float Q  = redS2[0] + redS2[1] + redS2[2] + redS2[3];
    float mean = S * (1.f / 256.f);
    float var  = Q * (1.f / 256.f) - mean * mean;
    float rstd = rsqrtf(var + 1e-5f);
    float xn = (v - mean) * rstd * gamma[tid] + beta[tid];
    kvs[tid] = xn;
    kvn[(size_t)row * 256 + tid] = f2us(xn);
    __syncthreads();
    {
      int oc = tid & 63, pp = tid >> 6;
      float acc = 0.f;
#pragma unroll 8
      for (int c = pp * 64; c < pp * 64 + 64; ++c)
        acc += kvs[c] * fcpw[c * 64 + oc];
      part[tid] = acc;
    }
    __syncthreads();
    if (tid < 64) {
      P2[(size_t)row * 64 + tid] = fcpb[tid] + part[tid] + part[64 + tid]
                                 + part[128 + tid] + part[192 + tid];
    } else if (tid < 80) {
      int i = tid - 64;
      int t = row & (T_ - 1);
      float ang = (float)pos[t] * __expf((float)(2*i) * -0.28782313657f);
      float c = __cosf(ang), s = __sinf(ang);
      float xr = (src[256 + 2*i] + src[PSk + 256 + 2*i])
               + (src[2*PSk + 256 + 2*i] + src[3*PSk + 256 + 2*i]);
      float xi = (src[257 + 2*i] + src[PSk + 257 + 2*i])
               + (src[2*PSk + 257 + 2*i] + src[3*PSk + 257 + 2*i]);
      kpe[(size_t)row * 32 + 2*i]     = f2us(xr * c - xi * s);
      kpe[(size_t)row * 32 + 2*i + 1] = f2us(xr * s + xi * c);
    }
  } else {
    // ---- C2[t] = sinusoid_pe(t/2) @ fc_c_w + b ----
    const int t = bid - 7168;
    float* pe   = fsm;
    float* part = fsm + 256;
    float p = (float)(t >> 1);
    if (tid < 128){
      float div = __expf((float)(2*tid) * -0.03597789207f);  // -ln(1e4)/256
      float a = p * div;
      pe[2*tid]   = __sinf(a);
      pe[2*tid+1] = __cosf(a);
    }
    __syncthreads();
    {
      int oc = tid & 63, pp = tid >> 6;
      float acc = 0.f;
#pragma unroll 8
      for (int c = pp * 64; c < pp * 64 + 64; ++c)
        acc += pe[c] * fccw[c * 64 + oc];
      part[tid] = acc;
    }
    __syncthreads();
    if (tid < 64)
      C2[t * 64 + tid] = fccb[tid] + part[tid] + part[64 + tid]
                       + part[128 + tid] + part[192 + tid];
  }
}

// ---------------- kv_t: block-diag (DR=2) temporal conv; 4 rows/block --------
__global__ __launch_bounds__(256) void kvt_kernel(const float* __restrict__ C2,
    const float* __restrict__ P2, const u16* __restrict__ kvn, u16* __restrict__ kvt)
{
  const int row = blockIdx.x * 4 + (threadIdx.x >> 6);   // 1024 blocks x 4 waves
  const int lane = threadIdx.x & 63;
  const int t = row & (T_ - 1);
  float c2v = C2[t * 64 + lane];
  float da = c2v * P2[(size_t)row * 64 + lane];
  for (int off = 1; off < 64; off <<= 1) da += __shfl_xor(da, off);
  float wtt = 1.f / (1.f + __expf(-da));
  const bool odd = (t & 1);
  float wts = 0.f;
  if (odd){
    float db = c2v * P2[(size_t)(row - 1) * 64 + lane];
    for (int off = 1; off < 64; off <<= 1) db += __shfl_xor(db, off);
    wts = 1.f / (1.f + __expf(-db));
  }
  for (int c = lane; c < 256; c += 64){
    float val = wtt * us2f(kvn[(size_t)row * 256 + c]);
    if (odd) val += wts * us2f(kvn[(size_t)(row - 1) * 256 + c]);
    kvt[(size_t)row * 256 + c] = f2us(val);
  }
}

// ---- fused: Vt transpose-gather (blocks 0..511) + Kc gather (blocks 512..2047) ----
// Kc is stored XOR-SWIZZLED within each 64-key tile: logical 16B chunk c (0..11)
// of local key kl lands at c' = (c&12) | ((c&3) ^ ((kl>>1)&3)).  attn_kernel
// stages tiles linearly via global_load_lds and applies the same XOR on ds_read,
// making the QK B-operand reads LDS bank-conflict-free (was 4-way).
__global__ __launch_bounds__(256) void vtkc_kernel(const u16* __restrict__ kvb,
    const u16* __restrict__ kpe, u16* __restrict__ Vt, u16* __restrict__ Kc)
{
  __shared__ __align__(16) u16 tile[64][72];
  const int tid = threadIdx.x;
  if (blockIdx.x < 512) {
    const int bid = blockIdx.x;
    const int jt = bid & 15;
    const int h  = (bid >> 4) & 15;
    const int b  = bid >> 8;
    const int jl = tid >> 2;
    const int dseg = (tid & 3) * 16;
    const int j0 = jt * 64;
    {
      int s_ = 2 * (j0 + jl) + 1;
      const u16* src = kvb + ((size_t)(b * T_ + s_)) * 2048 + h * 128 + 64 + dseg;
      *(u16x8*)&tile[jl][dseg]     = *(const u16x8*)(src);
      *(u16x8*)&tile[jl][dseg + 8] = *(const u16x8*)(src + 8);
    }
    __syncthreads();
    const int dl = tid >> 2;
    const int jseg = (tid & 3) * 16;
    u16* dst = Vt + ((size_t)(b * 16 + h) * 64 + dl) * 1024 + j0 + jseg;
    u16x8 o;
    for (int r = 0; r < 8; ++r) o[r] = tile[jseg + r][dl];
    *(u16x8*)dst = o;
    for (int r = 0; r < 8; ++r) o[r] = tile[jseg + 8 + r][dl];
    *(u16x8*)(dst + 8) = o;
  } else {
    int idx = (blockIdx.x - 512) * 256 + tid;   // 1536 blocks x 256 chunks
    int c  = idx % 12;
    int j  = (idx / 12) & 1023;
    int bh = idx / (12 * 1024);
    if (bh >= B_ * H_) return;
    int b = bh >> 4, h = bh & 15;
    int t = 2 * j + 1;
    u16x8 v;
    if (c < 8) v = *(const u16x8*)(kvb + ((size_t)(b * T_ + t)) * 2048 + h * 128 + c * 8);
    else       v = *(const u16x8*)(kpe + ((size_t)(b * T_ + t)) * 32 + (c - 8) * 8);
    int kl = j & 63;                              // local key within 64-key tile
    int cs = (c & 12) | ((c & 3) ^ ((kl >> 1) & 3));   // swizzled chunk slot
    *(u16x8*)(Kc + ((size_t)bh * 1024 + j) * 96 + cs * 8) = v;
  }
}

// ---- flash attention: fixed-max softmax, 64-key LDS chunks, one q-tile/block ----
// 1024 blocks (one qt each, big-qt first), 30KB LDS -> 16 waves/CU.
// Ks reads XOR-deswizzled (conflict-free).
__global__ __launch_bounds__(256) void attn_kernel(
    const u16* __restrict__ qh, const u16* __restrict__ kvb,
    const u16* __restrict__ kpe, const u16* __restrict__ Kc,
    const u16* __restrict__ Vt, u16* __restrict__ xout)
{
  __shared__ __align__(16) u16 Ks[64 * 96];        // 64 keys x 96 dims, swizzled
  __shared__ __align__(16) u16 Vs[64][72];         // 64 dims x 64 keys (+8 pad)
  __shared__ __align__(16) u16 pbufA[4][16 * 72];  // per-wave P: 16 q x 64 keys
  const int tid  = threadIdx.x;
  const int wid  = tid >> 6;
  const int lane = tid & 63;
  const int quad = lane >> 4;
  const int col  = lane & 15;
  const int qt   = 31 - (blockIdx.x >> 5);   // big q-tiles dispatched first
  const int bh   = blockIdx.x & 31;
  const int b    = bh >> 4;
  const int h    = bh & 15;
  u16* pbuf = pbufA[wid];
  const float scale = 0.10206207262f;   // 96^-0.5
  const u16* KcH = Kc + (size_t)bh * 1024 * 96;
  const u16* VtH = Vt + (size_t)bh * 64 * 1024;
  const int t0 = qt * 64 + wid * 16;
  const int qo = (quad * 8) ^ (((col >> 1) & 3) << 3);   // deswizzled read offset

  s16x8 aq0, aq1, aq2;
  {
    const u16* qrow = qh + ((size_t)bh * T_ + t0 + col) * 96;
    aq0 = ld8(qrow + quad * 8);
    aq1 = ld8(qrow + 32 + quad * 8);
    aq2 = ld8(qrow + 64 + quad * 8);
  }
  float sself;
  {
    const int t = t0 + col;
    const u16* qrow = qh + ((size_t)bh * T_ + t) * 96;
    const u16* ka = kvb + ((size_t)(b * T_ + t)) * 2048 + h * 128;
    const u16* kp = kpe + ((size_t)(b * T_ + t)) * 32;
    float a = 0.f;
#pragma unroll
    for (int c = 0; c < 8; ++c){
      u16x8 qv = *(const u16x8*)(qrow + c * 8);
      u16x8 kv = *(const u16x8*)(ka + c * 8);
#pragma unroll
      for (int jj = 0; jj < 8; ++jj) a += us2f(qv[jj]) * us2f(kv[jj]);
    }
#pragma unroll
    for (int c = 0; c < 4; ++c){
      u16x8 qv = *(const u16x8*)(qrow + 64 + c * 8);
      u16x8 kv = *(const u16x8*)(kp + c * 8);
#pragma unroll
      for (int jj = 0; jj < 8; ++jj) a += us2f(qv[jj]) * us2f(kv[jj]);
    }
    sself = a * scale;
  }
  float es[4], lacc[4];
  f32x4 O[4];
#pragma unroll
  for (int i = 0; i < 4; ++i){
    es[i] = __expf(__shfl(sself, quad * 4 + i));
    lacc[i] = 0.f;
  }
#pragma unroll
  for (int nt = 0; nt < 4; ++nt)
#pragma unroll
    for (int i = 0; i < 4; ++i){
      int t = t0 + quad * 4 + i;
      O[nt][i] = es[i] * us2f(kvb[((size_t)(b * T_ + t)) * 2048 + h * 128 + 64 + nt * 16 + col]);
    }

  const int nb = (qt * 32 + 94) >> 6;   // 64-key chunks, block-uniform
  for (int blk = 0; blk < nb; ++blk) {
    const int jb = blk * 64;
    __syncthreads();
    {
      // K tile: 12KB contiguous (pre-swizzled in global), linear async stage
      const u16* gk = KcH + (size_t)jb * 96 + (wid * 3) * 512 + lane * 8;
      u16* lk = &Ks[(wid * 3) * 512];
#pragma unroll
      for (int k = 0; k < 3; ++k)
        gload_lds16(gk + k * 512, lk + k * 512);
      // V tile: 64 dims x 64 keys, reg-staged into padded rows
      int d = tid >> 2, c4 = tid & 3;
      const u16* gv = VtH + (size_t)d * 1024 + jb + c4 * 16;
      u16* lv = &Vs[d][c4 * 16];
      *(u16x8*)(lv)     = *(const u16x8*)(gv);
      *(u16x8*)(lv + 8) = *(const u16x8*)(gv + 8);
    }
    __syncthreads();
#pragma unroll
    for (int cc = 0; cc < 2; ++cc){
      const u16* k0 = &Ks[(cc * 32 + col) * 96];
      const u16* k1 = k0 + 16 * 96;
      f32x4 s0 = {0,0,0,0}, s1 = {0,0,0,0};
      s0 = mfma32(aq0, ld8(k0 + qo), s0);
      s0 = mfma32(aq1, ld8(k0 + 32 + qo), s0);
      s0 = mfma32(aq2, ld8(k0 + 64 + qo), s0);
      s1 = mfma32(aq0, ld8(k1 + qo), s1);
      s1 = mfma32(aq1, ld8(k1 + 32 + qo), s1);
      s1 = mfma32(aq2, ld8(k1 + 64 + qo), s1);
      int key0 = jb + cc * 32 + col;
#pragma unroll
      for (int i = 0; i < 4; ++i){
        int lim = (t0 + quad * 4 + i) >> 1;
        float p0 = (key0 < lim)      ? __expf(s0[i] * scale) : 0.f;
        float p1 = (key0 + 16 < lim) ? __expf(s1[i] * scale) : 0.f;
        lacc[i] += p0 + p1;
        pbuf[(quad * 4 + i) * 72 + cc * 32 + col]      = f2us(p0);
        pbuf[(quad * 4 + i) * 72 + cc * 32 + 16 + col] = f2us(p1);
      }
    }
    asm volatile("s_waitcnt lgkmcnt(0)" ::: "memory");
    __builtin_amdgcn_sched_barrier(0);
#pragma unroll
    for (int cc = 0; cc < 2; ++cc){
      s16x8 pf = ld8(&pbuf[col * 72 + cc * 32 + quad * 8]);
#pragma unroll
      for (int nt = 0; nt < 4; ++nt)
        O[nt] = mfma32(pf, ld8(&Vs[nt * 16 + col][cc * 32 + quad * 8]), O[nt]);
    }
  }
#pragma unroll
  for (int i = 0; i < 4; ++i){
    float l = lacc[i];
    l += __shfl_xor(l, 1);
    l += __shfl_xor(l, 2);
    l += __shfl_xor(l, 4);
    l += __shfl_xor(l, 8);
    lacc[i] = es[i] + l;
  }
#pragma unroll
  for (int nt = 0; nt < 4; ++nt)
#pragma unroll
    for (int i = 0; i < 4; ++i){
      int t = t0 + quad * 4 + i;
      xout[((size_t)(b * T_ + t)) * 1024 + h * 64 + nt * 16 + col] = f2us(O[nt][i] / lacc[i]);
    }
}

extern "C" void kernel_launch(void* const* d_in, const int* in_sizes, int n_in,
                              void* d_out, int out_size, void* d_ws, size_t ws_size,
                              hipStream_t stream)
{
  (void)in_sizes; (void)n_in; (void)out_size; (void)ws_size;
  const float* query = (const float*)d_in[0];
  const float* key_  = (const float*)d_in[1];
  const int*   pos   = (const int*)d_in[3];
  const float* wq    = (const float*)d_in[4];
  const float* wkva  = (const float*)d_in[5];
  const float* gamma = (const float*)d_in[6];
  const float* beta  = (const float*)d_in[7];
  const float* wkvb  = (const float*)d_in[8];
  const float* wo    = (const float*)d_in[9];
  const float* fccw  = (const float*)d_in[10];
  const float* fccb  = (const float*)d_in[11];
  const float* fcpw  = (const float*)d_in[12];
  const float* fcpb  = (const float*)d_in[13];

  char* p = (char*)d_ws;
  auto alloc = [&](size_t bytes) -> void* {
    void* r = (void*)p;
    p += (bytes + 255) & ~(size_t)255;
    return r;
  };
  u16* wqT    = (u16*)alloc(1536ull * 2048 * 2);
  u16* wkvaT  = (u16*)alloc(288ull  * 2048 * 2);
  u16* woT    = (u16*)alloc(2048ull * 1024 * 2);
  u16* wkvbB  = (u16*)alloc(2048ull * 256 * 2);
  u16* queryB = (u16*)alloc(4096ull * 2048 * 2);
  u16* keyB   = (u16*)alloc(4096ull * 2048 * 2);
  u16* qp     = (u16*)alloc(2ull * 4096 * 1536 * 2);  // 2 split-K partials (25.2MB)
  float* kvp  = (float*)alloc(4ull * 4096 * 288 * 4); // 4 f32 key-proj partials (18.9MB)
  u16* qh     = (u16*)alloc(65536ull * 96 * 2);    // (B,H,T,96)
  u16* kvn    = (u16*)alloc(4096ull * 256 * 2);
  u16* kpe    = (u16*)alloc(4096ull * 32 * 2);
  float* P2   = (float*)alloc(4096ull * 64 * 4);
  float* C2   = (float*)alloc(2048ull * 64 * 4);
  u16* kvt    = (u16*)alloc(4096ull * 256 * 2);
  u16* kvb    = (u16*)alloc(4096ull * 2048 * 2);   // per-head [k_abs(64)|v(64)]
  // qp is dead after mid3; Kc/Vt/x are born at vtkc/attn -> alias onto qp
  char* q8 = (char*)qp;
  u16* Kc = (u16*)q8;                                    // 6.29MB (B,H,1024,96)
  u16* Vt = (u16*)(q8 + ((32ull*1024*96*2 + 255) & ~255ull));      // 4.19MB
  u16* x  = (u16*)(q8 + ((32ull*1024*96*2 + 255) & ~255ull)
                      + ((2048ull*1024*2   + 255) & ~255ull));     // 8.39MB

  prep_cvt<<<22592, 256, 0, stream>>>(wq, wkva, wo, wkvb, query, key_,
                                      wqT, wkvaT, woT, wkvbB, queryB, keyB);
  proj2<<<2048, 256, 0, stream>>>(queryB, wqT, qp, keyB, wkvaT, kvp);
  mid3<<<9216, 256, 0, stream>>>(qp, pos, qh, kvp, gamma, beta, fcpw, fcpb,
                                 kvn, P2, kpe, fccw, fccb, C2);
  kvt_kernel<<<1024, 256, 0, stream>>>(C2, P2, kvn, kvt);

  gemm128<0><<<512, 256, 0, stream>>>(kvt, wkvbB, kvb, 4096, 2048, 256, 16);
  vtkc_kernel<<<2048, 256, 0, stream>>>(kvb, kpe, Vt, Kc);
  attn_kernel<<<1024, 256, 0, stream>>>(qh, kvb, kpe, Kc, Vt, x);

  gemm128<1><<<512, 256, 0, stream>>>(x, woT, d_out, 4096, 2048, 1024, 16);
}

// Round 9
// 331.988 us; speedup vs baseline: 1.0269x; 1.0016x over previous
//
#include <hip/hip_runtime.h>
#include <stddef.h>

typedef unsigned short u16;
typedef unsigned short u16x8 __attribute__((ext_vector_type(8)));
typedef short s16x8 __attribute__((ext_vector_type(8)));
typedef float f32x4 __attribute__((ext_vector_type(4)));

#define B_ 2
#define T_ 2048
#define E_ 2048
#define H_ 16

__device__ inline float us2f(u16 u){
  unsigned int i = ((unsigned int)u) << 16;
  return __builtin_bit_cast(float, i);
}
__device__ inline u16 f2us(float f){
  unsigned int x = __builtin_bit_cast(unsigned int, f);
  unsigned int r = (x + 0x7fffu + ((x >> 16) & 1u)) >> 16;
  return (u16)r;
}
__device__ inline f32x4 mfma32(s16x8 a, s16x8 b, f32x4 c){
  return __builtin_amdgcn_mfma_f32_16x16x32_bf16(a, b, c, 0, 0, 0);
}
__device__ inline s16x8 ld8(const u16* p){
  return __builtin_bit_cast(s16x8, *(const u16x8*)p);
}
// async global->LDS, 16B per lane; LDS dest = wave-uniform base + lane*16 (m97/m104)
__device__ inline void gload_lds16(const u16* g, u16* l){
  __builtin_amdgcn_global_load_lds(
      (const __attribute__((address_space(1))) unsigned int*)(g),
      (__attribute__((address_space(3))) unsigned int*)(l), 16, 0, 0);
}

// ==== FUSED stage 1: weight prep (transposes + cvt) U input cvt; independent ====
// blocks [0,5696): transposes; [5696,6208): wkvb cvt; [6208,22592): query/key cvt
__global__ __launch_bounds__(256) void prep_cvt(
    const float* __restrict__ wq, const float* __restrict__ wkva,
    const float* __restrict__ wo, const float* __restrict__ wkvb,
    const float* __restrict__ query, const float* __restrict__ key_,
    u16* __restrict__ wqT, u16* __restrict__ wkvaT, u16* __restrict__ woT,
    u16* __restrict__ wkvbB, u16* __restrict__ queryB, u16* __restrict__ keyB)
{
  __shared__ float tile[32][33];
  const int bid = blockIdx.x;
  const int tid = threadIdx.x;
  if (bid < 5696) {
    const float* in; u16* out; int R, C, bx, by;
    if (bid < 3072)      { in = wq;   out = wqT;   R = 2048; C = 1536; bx = bid % 48;          by = bid / 48; }
    else if (bid < 3648) { in = wkva; out = wkvaT; R = 2048; C = 288;  bx = (bid-3072) % 9;    by = (bid-3072) / 9; }
    else                 { in = wo;   out = woT;   R = 1024; C = 2048; bx = (bid-3648) % 64;   by = (bid-3648) / 64; }
    int tx = tid & 31, ty = tid >> 5;   // 32 x 8
    int c0 = bx * 32, r0 = by * 32;
    for (int i = ty; i < 32; i += 8){
      int r = r0 + i, c = c0 + tx;
      tile[i][tx] = (r < R && c < C) ? in[(size_t)r * C + c] : 0.f;
    }
    __syncthreads();
    for (int i = ty; i < 32; i += 8){
      int c = c0 + i, r = r0 + tx;
      if (c < C && r < R) out[(size_t)c * R + r] = f2us(tile[tx][i]);
    }
  } else if (bid < 6208) {
    int i = (bid - 5696) * 1024 + tid * 4;   // 512 blocks x 1024 elems = 2048*256
    f32x4 v = *(const f32x4*)(wkvb + i);
    wkvbB[i]   = f2us(v[0]); wkvbB[i+1] = f2us(v[1]);
    wkvbB[i+2] = f2us(v[2]); wkvbB[i+3] = f2us(v[3]);
  } else {
    const int n_each = 4096 * 2048;
    int idx = (bid - 6208) * 1024 + tid * 4;
    const float* in; u16* out; int i;
    if (idx < n_each){ in = query; out = queryB; i = idx; }
    else             { in = key_;  out = keyB;   i = idx - n_each; }
    if (i + 3 < n_each){
      f32x4 v = *(const f32x4*)(in + i);
      out[i]   = f2us(v[0]); out[i+1] = f2us(v[1]);
      out[i+2] = f2us(v[2]); out[i+3] = f2us(v[3]);
    }
  }
}

// ==== FUSED stage 2, round-12: INTERLEAVED q-proj U key-proj, DEPTH-2 PIPELINE ====
// R8 audit: the "2-phase" loop's vmcnt(0) waited for the STAGE issued ~300cyc earlier
// in the SAME iteration -> pipeline depth was ZERO; every K-step ate ~600cyc of cold
// HBM latency (FETCH 42MB == one-pass footprint, so loads are first-touch misses; L2
// can't help).  T4 fix: TRIPLE-buffer LDS; at iter it issue STAGE(tile it+2); wait
// vmcnt(4) (tile it+1 drained, it+2's 4 loads stay in flight across the barrier).
// Safety: buf[(it+2)%3] holds tile it-1, whose reads all waves finished before the
// previous barrier (lgkmcnt(0) precedes it).  Tail: vmcnt(0) when it+2>=nt.
// Roles interleaved 3:5 in bid-space (R8-verified); per-XCD contiguous ids for L2.
__global__ __launch_bounds__(256) void proj2(
    const u16* __restrict__ queryB, const u16* __restrict__ wqT, u16* __restrict__ qp,
    const u16* __restrict__ keyB, const u16* __restrict__ wkvaT, float* __restrict__ kvp)
{
  __shared__ __align__(16) u16 smem[24576];   // sk: As[0..12288) Bs[12288..24576); bt: 5120 used
  const int bid = blockIdx.x;
  const int tid  = threadIdx.x;
  const int lane = tid & 63;
  const int wid  = tid >> 6;
  const int quad = lane >> 4;
  const int col  = lane & 15;
  const int g  = bid >> 3;
  const int e  = bid & 7;      // XCD (round-robin assumption)
  const int gm = g & 7;

  if (gm < 3) {
    // ---- sk: split-K=2 3-buffer 128x128 GEMM: M=4096 N=1536 K=2048 Klen=1024 ----
    const int id = e * 96 + (g >> 3) * 3 + gm;     // 0..767, per-XCD contiguous
    const int kh   = id / 384;
    const int r2   = id % 384;
    const int bmHi = r2 / 48;
    const int r3   = r2 % 48;
    const int bn = (r3 >> 2) * 128;
    const int bm = (bmHi * 4 + (r3 & 3)) * 128;
    const int N = 1536, K = 2048, Klen = 1024;
    const int waveM = wid >> 1, waveN = wid & 1;
    u16* As = smem;
    u16* Bs = smem + 12288;

    const int srow = wid * 16 + (lane >> 2);
    const int scol = (lane & 3) * 8;
    const u16* ga = queryB + (size_t)(bm + srow) * K + kh * Klen + scol;
    const u16* gb = wqT    + (size_t)(bn + srow) * K + kh * Klen + scol;
    const size_t rowskip = (size_t)64 * K;
    u16* Cp = qp + (size_t)kh * 4096 * N;

    f32x4 acc[4][4] = {};
    const int nt = Klen >> 5;   // 32

    auto STAGE = [&](int buf, int kk){
      u16* la = &As[buf * 4096 + wid * 512];
      u16* lb = &Bs[buf * 4096 + wid * 512];
      gload_lds16(ga + kk,           la);
      gload_lds16(ga + rowskip + kk, la + 2048);
      gload_lds16(gb + kk,           lb);
      gload_lds16(gb + rowskip + kk, lb + 2048);
    };

    STAGE(0, 0);
    STAGE(1, 32);
    asm volatile("s_waitcnt vmcnt(4)" ::: "memory");   // tile 0 landed; tile 1 in flight
    __builtin_amdgcn_s_barrier();
    __builtin_amdgcn_sched_barrier(0);

    int bc = 0;
    for (int it = 0; it < nt; ++it){
      if (it + 2 < nt){
        int bs = bc + 2; if (bs >= 3) bs -= 3;
        STAGE(bs, (it + 2) * 32);
      }
      const u16* as = &As[bc * 4096];
      const u16* bs_ = &Bs[bc * 4096];
      s16x8 af[4], bf[4];
#pragma unroll
      for (int i = 0; i < 4; ++i) af[i] = ld8(&as[(waveM*64 + i*16 + col) * 32 + quad*8]);
#pragma unroll
      for (int i = 0; i < 4; ++i) bf[i] = ld8(&bs_[(waveN*64 + i*16 + col) * 32 + quad*8]);
      __builtin_amdgcn_s_setprio(1);
#pragma unroll
      for (int i = 0; i < 4; ++i)
#pragma unroll
        for (int j = 0; j < 4; ++j)
          acc[i][j] = mfma32(af[i], bf[j], acc[i][j]);
      __builtin_amdgcn_s_setprio(0);
      asm volatile("s_waitcnt lgkmcnt(0)" ::: "memory");
      if (it + 2 < nt)
        asm volatile("s_waitcnt vmcnt(4)" ::: "memory");   // next tile drained; newest stays in flight
      else
        asm volatile("s_waitcnt vmcnt(0)" ::: "memory");
      __builtin_amdgcn_s_barrier();
      __builtin_amdgcn_sched_barrier(0);
      bc += 1; if (bc == 3) bc = 0;
    }
#pragma unroll
    for (int i = 0; i < 4; ++i)
#pragma unroll
      for (int j = 0; j < 4; ++j)
#pragma unroll
        for (int r = 0; r < 4; ++r) {
          int row = bm + waveM*64 + i*16 + quad*4 + r;
          int c   = bn + waveN*64 + j*16 + col;
          Cp[(size_t)row * N + c] = f2us(acc[i][j][r]);
        }
  } else {
    // ---- bt: split-K=4 reg-prefetch 64x64 GEMM: kvp[kh] = keyB@wkvaT^T slice ----
    const int id = e * 160 + (g >> 3) * 5 + (gm - 3);   // 0..1279, per-XCD contiguous
    const int kh = id / 320;
    const int r  = id % 320;
    const int bm = (r / 5) * 64;
    const int bn = (r % 5) * 64;
    const int N = 288, K = 2048, Klen = 512;
    const int lr = tid >> 2;
    const int lc = (tid & 3) * 8;
    const int waveM = wid >> 1, waveN = wid & 1;
    u16* As = smem;                    // [64][40] padded (conflict-free ds_read)
    u16* Bs = smem + 2560;

    f32x4 acc[2][2];
    for (int i = 0; i < 2; ++i)
      for (int j = 0; j < 2; ++j)
        acc[i][j] = (f32x4){0.f, 0.f, 0.f, 0.f};

    const u16x8 zero8 = {0,0,0,0,0,0,0,0};
    const bool bok = (bn + lr) < N;
    const u16* arow = keyB  + (size_t)(bm + lr) * K + kh * Klen + lc;
    const u16* brow = wkvaT + (size_t)(bn + lr) * K + kh * Klen + lc;
    float* Cp = kvp + (size_t)kh * 4096 * N;

    u16x8 av = *(const u16x8*)(arow);
    u16x8 bv = bok ? *(const u16x8*)(brow) : zero8;
    for (int kk = 0; kk < Klen; kk += 32) {
      __syncthreads();
      *(u16x8*)&As[lr*40 + lc] = av;
      *(u16x8*)&Bs[lr*40 + lc] = bv;
      if (kk + 32 < Klen){                       // issue next-step loads now;
        av = *(const u16x8*)(arow + kk + 32);    // ds_read+MFMA below covers latency
        bv = bok ? *(const u16x8*)(brow + kk + 32) : zero8;
      }
      __syncthreads();
      s16x8 af0 = ld8(&As[(waveM*32 + col)*40 + quad*8]);
      s16x8 af1 = ld8(&As[(waveM*32 + 16 + col)*40 + quad*8]);
      s16x8 bf0 = ld8(&Bs[(waveN*32 + col)*40 + quad*8]);
      s16x8 bf1 = ld8(&Bs[(waveN*32 + 16 + col)*40 + quad*8]);
      acc[0][0] = mfma32(af0, bf0, acc[0][0]);
      acc[0][1] = mfma32(af0, bf1, acc[0][1]);
      acc[1][0] = mfma32(af1, bf0, acc[1][0]);
      acc[1][1] = mfma32(af1, bf1, acc[1][1]);
    }
    for (int am = 0; am < 2; ++am)
      for (int bnn = 0; bnn < 2; ++bnn)
        for (int i = 0; i < 4; ++i) {
          int rr = bm + waveM*32 + am*16 + quad*4 + i;
          int c  = bn + waveN*32 + bnn*16 + col;
          if (c < N) Cp[(size_t)rr * N + c] = acc[am][bnn][i];
        }
  }
}

// ------- 3-buffer depth-2 128x128 GEMM (T4 counted-vmcnt, XCD-swizzled) -------
// Round-12: STAGE(tile it+2) at top; vmcnt(4) at bottom keeps the newest 4 loads
// in flight across the barrier (drains only tile it+1).  48KB LDS -> 3 blocks/CU.
template<int OUT_F32>
__global__ __launch_bounds__(256) void gemm128(const u16* __restrict__ A,
    const u16* __restrict__ Bt, void* __restrict__ Cp, int M, int N, int K, int gx)
{
  __shared__ __align__(16) u16 As[3 * 128 * 32];
  __shared__ __align__(16) u16 Bs[3 * 128 * 32];
  const int lin = blockIdx.x;
  const int cpx = gridDim.x >> 3;
  const int swz = (lin & 7) * cpx + (lin >> 3);
  const int bxi = swz % gx;
  const int byi = swz / gx;
  const int tid  = threadIdx.x;
  const int lane = tid & 63;
  const int wid  = tid >> 6;
  const int quad = lane >> 4;
  const int col  = lane & 15;
  const int bm = byi * 128;
  const int bn = bxi * 128;
  const int waveM = wid >> 1, waveN = wid & 1;

  const int srow = wid * 16 + (lane >> 2);
  const int scol = (lane & 3) * 8;
  const u16* ga = A  + (size_t)(bm + srow) * K + scol;
  const u16* gb = Bt + (size_t)(bn + srow) * K + scol;
  const size_t rowskip = (size_t)64 * K;

  f32x4 acc[4][4] = {};
  const int nt = K >> 5;

  auto STAGE = [&](int buf, int kk){
    u16* la = &As[buf * 4096 + wid * 512];
    u16* lb = &Bs[buf * 4096 + wid * 512];
    gload_lds16(ga + kk,           la);
    gload_lds16(ga + rowskip + kk, la + 2048);
    gload_lds16(gb + kk,           lb);
    gload_lds16(gb + rowskip + kk, lb + 2048);
  };

  STAGE(0, 0);
  if (nt > 1){
    STAGE(1, 32);
    asm volatile("s_waitcnt vmcnt(4)" ::: "memory");   // tile 0 landed
  } else {
    asm volatile("s_waitcnt vmcnt(0)" ::: "memory");
  }
  __builtin_amdgcn_s_barrier();
  __builtin_amdgcn_sched_barrier(0);

  int bc = 0;
  for (int it = 0; it < nt; ++it){
    if (it + 2 < nt){
      int bs = bc + 2; if (bs >= 3) bs -= 3;
      STAGE(bs, (it + 2) * 32);
    }
    const u16* as = &As[bc * 4096];
    const u16* bs_ = &Bs[bc * 4096];
    s16x8 af[4], bf[4];
#pragma unroll
    for (int i = 0; i < 4; ++i) af[i] = ld8(&as[(waveM*64 + i*16 + col) * 32 + quad*8]);
#pragma unroll
    for (int i = 0; i < 4; ++i) bf[i] = ld8(&bs_[(waveN*64 + i*16 + col) * 32 + quad*8]);
#pragma unroll
    for (int i = 0; i < 4; ++i)
#pragma unroll
      for (int j = 0; j < 4; ++j)
        acc[i][j] = mfma32(af[i], bf[j], acc[i][j]);
    asm volatile("s_waitcnt lgkmcnt(0)" ::: "memory");
    if (it + 2 < nt)
      asm volatile("s_waitcnt vmcnt(4)" ::: "memory");
    else
      asm volatile("s_waitcnt vmcnt(0)" ::: "memory");
    __builtin_amdgcn_s_barrier();
    __builtin_amdgcn_sched_barrier(0);
    bc += 1; if (bc == 3) bc = 0;
  }
#pragma unroll
  for (int i = 0; i < 4; ++i)
#pragma unroll
    for (int j = 0; j < 4; ++j)
#pragma unroll
      for (int r = 0; r < 4; ++r) {
        int row = bm + waveM*64 + i*16 + quad*4 + r;
        int c   = bn + waveN*64 + j*16 + col;
        if (OUT_F32) ((float*)Cp)[(size_t)row * N + c] = acc[i][j][r];
        else         ((u16*)Cp)[(size_t)row * N + c]   = f2us(acc[i][j][r]);
      }
}

// ==== FUSED stage 3: qsplit (2 bf16 partials) U ln_p2_rope (4 f32 kvp partials) U c2 ====
// blocks [0,3072): qsplit; [3072,7168): ln_p2_rope; [7168,9216): c2
__global__ __launch_bounds__(256) void mid3(
    const u16* __restrict__ qp, const int* __restrict__ pos, u16* __restrict__ qh,
    const float* __restrict__ kvp, const float* __restrict__ gamma,
    const float* __restrict__ beta, const float* __restrict__ fcpw,
    const float* __restrict__ fcpb, u16* __restrict__ kvn,
    float* __restrict__ P2, u16* __restrict__ kpe,
    const float* __restrict__ fccw, const float* __restrict__ fccb,
    float* __restrict__ C2)
{
  __shared__ float fsm[520];    // ln: kvs[256]+part[256]+redS[4]+redS2[4]; c2: pe+part
  const int bid = blockIdx.x;
  const int tid = threadIdx.x;

  if (bid < 3072) {
    // ---- qsplit: combine 2 split-K partials + rope dims 64..95 ----
    const size_t PS = 4096ull * 1536;
    int idx = bid * 256 + tid;
    int c    = idx % 12;
    int rest = idx / 12;
    int h    = rest & 15;
    int row  = rest >> 4;
    int t    = row & (T_ - 1);
    int b    = row >> 11;
    size_t off = (size_t)row * 1536 + h * 96 + c * 8;
    u16x8 v0 = *(const u16x8*)(qp + off);
    u16x8 v1 = *(const u16x8*)(qp + PS + off);
    u16x8 v;
    if (c < 8) {
#pragma unroll
      for (int k = 0; k < 8; ++k) v[k] = f2us(us2f(v0[k]) + us2f(v1[k]));
    } else {
      int i0 = (c - 8) * 4;
      float pp = (float)pos[t];
#pragma unroll
      for (int k = 0; k < 4; ++k){
        int i = i0 + k;
        float ang = pp * __expf((float)(2*i) * -0.28782313657f); // -ln(1e4)/32
        float cs = __cosf(ang), sn = __sinf(ang);
        float xr = us2f(v0[2*k])   + us2f(v1[2*k]);
        float xi = us2f(v0[2*k+1]) + us2f(v1[2*k+1]);
        v[2*k]   = f2us(xr * cs - xi * sn);
        v[2*k+1] = f2us(xr * sn + xi * cs);
      }
    }
    u16* dst = qh + ((size_t)(b * 16 + h) * T_ + t) * 96;
    *(u16x8*)(dst + c * 8) = v;
  } else if (bid < 7168) {
    // ---- layernorm(sum of 4 kvp partials) + P2 + rope(k_pe) ----
    const int row = bid - 3072;
    const int lane = tid & 63, wid = tid >> 6;
    const size_t PSk = 4096ull * 288;
    float* kvs   = fsm;
    float* part  = fsm + 256;
    float* redS  = fsm + 512;
    float* redS2 = fsm + 516;
    const float* src = kvp + (size_t)row * 288;
    float v = (src[tid] + src[PSk + tid]) + (src[2*PSk + tid] + src[3*PSk + tid]);
    float s1 = v, s2 = v * v;
    for (int off = 1; off < 64; off <<= 1){
      s1 += __shfl_xor(s1, off);
      s2 += __shfl_xor(s2, off);
    }
    if (lane == 0){ redS[wid] = s1; redS2[wid] = s2; }
    __syncthreads();
    float S  = redS[0] + redS[1] + redS[2] + redS[3];
    float Q  = redS2[0] + redS2[1] + redS2[2] + redS2[3];
    float mean = S * (1.f / 256.f);
    float var  = Q * (1.f / 256.f) - mean * mean;
    float rstd = rsqrtf(var + 1e-5f);
    float xn = (v - mean) * rstd * gamma[tid] + beta[tid];
    kvs[tid] = xn;
    kvn[(size_t)row * 256 + tid] = f2us(xn);
    __syncthreads();
    {
      int oc = tid & 63, pp = tid >> 6;
      float acc = 0.f;
#pragma unroll 8
      for (int c = pp * 64; c < pp * 64 + 64; ++c)
        acc += kvs[c] * fcpw[c * 64 + oc];
      part[tid] = acc;
    }
    __syncthreads();
    if (tid < 64) {
      P2[(size_t)row * 64 + tid] = fcpb[tid] + part[tid] + part[64 + tid]
                                 + part[128 + tid] + part[192 + tid];
    } else if (tid < 80) {
      int i = tid - 64;
      int t = row & (T_ - 1);
      float ang = (float)pos[t] * __expf((float)(2*i) * -0.28782313657f);
      float c = __cosf(ang), s = __sinf(ang);
      float xr = (src[256 + 2*i] + src[PSk + 256 + 2*i])
               + (src[2*PSk + 256 + 2*i] + src[3*PSk + 256 + 2*i]);
      float xi = (src[257 + 2*i] + src[PSk + 257 + 2*i])
               + (src[2*PSk + 257 + 2*i] + src[3*PSk + 257 + 2*i]);
      kpe[(size_t)row * 32 + 2*i]     = f2us(xr * c - xi * s);
      kpe[(size_t)row * 32 + 2*i + 1] = f2us(xr * s + xi * c);
    }
  } else {
    // ---- C2[t] = sinusoid_pe(t/2) @ fc_c_w + b ----
    const int t = bid - 7168;
    float* pe   = fsm;
    float* part = fsm + 256;
    float p = (float)(t >> 1);
    if (tid < 128){
      float div = __expf((float)(2*tid) * -0.03597789207f);  // -ln(1e4)/256
      float a = p * div;
      pe[2*tid]   = __sinf(a);
      pe[2*tid+1] = __cosf(a);
    }
    __syncthreads();
    {
      int oc = tid & 63, pp = tid >> 6;
      float acc = 0.f;
#pragma unroll 8
      for (int c = pp * 64; c < pp * 64 + 64; ++c)
        acc += pe[c] * fccw[c * 64 + oc];
      part[tid] = acc;
    }
    __syncthreads();
    if (tid < 64)
      C2[t * 64 + tid] = fccb[tid] + part[tid] + part[64 + tid]
                       + part[128 + tid] + part[192 + tid];
  }
}

// ---------------- kv_t: block-diag (DR=2) temporal conv; 4 rows/block --------
__global__ __launch_bounds__(256) void kvt_kernel(const float* __restrict__ C2,
    const float* __restrict__ P2, const u16* __restrict__ kvn, u16* __restrict__ kvt)
{
  const int row = blockIdx.x * 4 + (threadIdx.x >> 6);   // 1024 blocks x 4 waves
  const int lane = threadIdx.x & 63;
  const int t = row & (T_ - 1);
  float c2v = C2[t * 64 + lane];
  float da = c2v * P2[(size_t)row * 64 + lane];
  for (int off = 1; off < 64; off <<= 1) da += __shfl_xor(da, off);
  float wtt = 1.f / (1.f + __expf(-da));
  const bool odd = (t & 1);
  float wts = 0.f;
  if (odd){
    float db = c2v * P2[(size_t)(row - 1) * 64 + lane];
    for (int off = 1; off < 64; off <<= 1) db += __shfl_xor(db, off);
    wts = 1.f / (1.f + __expf(-db));
  }
  for (int c = lane; c < 256; c += 64){
    float val = wtt * us2f(kvn[(size_t)row * 256 + c]);
    if (odd) val += wts * us2f(kvn[(size_t)(row - 1) * 256 + c]);
    kvt[(size_t)row * 256 + c] = f2us(val);
  }
}

// ---- fused: Vt transpose-gather (blocks 0..511) + Kc gather (blocks 512..2047) ----
// Kc is stored XOR-SWIZZLED within each 64-key tile: logical 16B chunk c (0..11)
// of local key kl lands at c' = (c&12) | ((c&3) ^ ((kl>>1)&3)).  attn_kernel
// stages tiles linearly via global_load_lds and applies the same XOR on ds_read,
// making the QK B-operand reads LDS bank-conflict-free (was 4-way).
__global__ __launch_bounds__(256) void vtkc_kernel(const u16* __restrict__ kvb,
    const u16* __restrict__ kpe, u16* __restrict__ Vt, u16* __restrict__ Kc)
{
  __shared__ __align__(16) u16 tile[64][72];
  const int tid = threadIdx.x;
  if (blockIdx.x < 512) {
    const int bid = blockIdx.x;
    const int jt = bid & 15;
    const int h  = (bid >> 4) & 15;
    const int b  = bid >> 8;
    const int jl = tid >> 2;
    const int dseg = (tid & 3) * 16;
    const int j0 = jt * 64;
    {
      int s_ = 2 * (j0 + jl) + 1;
      const u16* src = kvb + ((size_t)(b * T_ + s_)) * 2048 + h * 128 + 64 + dseg;
      *(u16x8*)&tile[jl][dseg]     = *(const u16x8*)(src);
      *(u16x8*)&tile[jl][dseg + 8] = *(const u16x8*)(src + 8);
    }
    __syncthreads();
    const int dl = tid >> 2;
    const int jseg = (tid & 3) * 16;
    u16* dst = Vt + ((size_t)(b * 16 + h) * 64 + dl) * 1024 + j0 + jseg;
    u16x8 o;
    for (int r = 0; r < 8; ++r) o[r] = tile[jseg + r][dl];
    *(u16x8*)dst = o;
    for (int r = 0; r < 8; ++r) o[r] = tile[jseg + 8 + r][dl];
    *(u16x8*)(dst + 8) = o;
  } else {
    int idx = (blockIdx.x - 512) * 256 + tid;   // 1536 blocks x 256 chunks
    int c  = idx % 12;
    int j  = (idx / 12) & 1023;
    int bh = idx / (12 * 1024);
    if (bh >= B_ * H_) return;
    int b = bh >> 4, h = bh & 15;
    int t = 2 * j + 1;
    u16x8 v;
    if (c < 8) v = *(const u16x8*)(kvb + ((size_t)(b * T_ + t)) * 2048 + h * 128 + c * 8);
    else       v = *(const u16x8*)(kpe + ((size_t)(b * T_ + t)) * 32 + (c - 8) * 8);
    int kl = j & 63;                              // local key within 64-key tile
    int cs = (c & 12) | ((c & 3) ^ ((kl >> 1) & 3));   // swizzled chunk slot
    *(u16x8*)(Kc + ((size_t)bh * 1024 + j) * 96 + cs * 8) = v;
  }
}

// ---- flash attention: fixed-max softmax, 64-key LDS chunks, one q-tile/block ----
// 1024 blocks (one qt each, big-qt first), 30KB LDS -> 16 waves/CU.
// Ks reads XOR-deswizzled (conflict-free).
__global__ __launch_bounds__(256) void attn_kernel(
    const u16* __restrict__ qh, const u16* __restrict__ kvb,
    const u16* __restrict__ kpe, const u16* __restrict__ Kc,
    const u16* __restrict__ Vt, u16* __restrict__ xout)
{
  __shared__ __align__(16) u16 Ks[64 * 96];        // 64 keys x 96 dims, swizzled
  __shared__ __align__(16) u16 Vs[64][72];         // 64 dims x 64 keys (+8 pad)
  __shared__ __align__(16) u16 pbufA[4][16 * 72];  // per-wave P: 16 q x 64 keys
  const int tid  = threadIdx.x;
  const int wid  = tid >> 6;
  const int lane = tid & 63;
  const int quad = lane >> 4;
  const int col  = lane & 15;
  const int qt   = 31 - (blockIdx.x >> 5);   // big q-tiles dispatched first
  const int bh   = blockIdx.x & 31;
  const int b    = bh >> 4;
  const int h    = bh & 15;
  u16* pbuf = pbufA[wid];
  const float scale = 0.10206207262f;   // 96^-0.5
  const u16* KcH = Kc + (size_t)bh * 1024 * 96;
  const u16* VtH = Vt + (size_t)bh * 64 * 1024;
  const int t0 = qt * 64 + wid * 16;
  const int qo = (quad * 8) ^ (((col >> 1) & 3) << 3);   // deswizzled read offset

  s16x8 aq0, aq1, aq2;
  {
    const u16* qrow = qh + ((size_t)bh * T_ + t0 + col) * 96;
    aq0 = ld8(qrow + quad * 8);
    aq1 = ld8(qrow + 32 + quad * 8);
    aq2 = ld8(qrow + 64 + quad * 8);
  }
  float sself;
  {
    const int t = t0 + col;
    const u16* qrow = qh + ((size_t)bh * T_ + t) * 96;
    const u16* ka = kvb + ((size_t)(b * T_ + t)) * 2048 + h * 128;
    const u16* kp = kpe + ((size_t)(b * T_ + t)) * 32;
    float a = 0.f;
#pragma unroll
    for (int c = 0; c < 8; ++c){
      u16x8 qv = *(const u16x8*)(qrow + c * 8);
      u16x8 kv = *(const u16x8*)(ka + c * 8);
#pragma unroll
      for (int jj = 0; jj < 8; ++jj) a += us2f(qv[jj]) * us2f(kv[jj]);
    }
#pragma unroll
    for (int c = 0; c < 4; ++c){
      u16x8 qv = *(const u16x8*)(qrow + 64 + c * 8);
      u16x8 kv = *(const u16x8*)(kp + c * 8);
#pragma unroll
      for (int jj = 0; jj < 8; ++jj) a += us2f(qv[jj]) * us2f(kv[jj]);
    }
    sself = a * scale;
  }
  float es[4], lacc[4];
  f32x4 O[4];
#pragma unroll
  for (int i = 0; i < 4; ++i){
    es[i] = __expf(__shfl(sself, quad * 4 + i));
    lacc[i] = 0.f;
  }
#pragma unroll
  for (int nt = 0; nt < 4; ++nt)
#pragma unroll
    for (int i = 0; i < 4; ++i){
      int t = t0 + quad * 4 + i;
      O[nt][i] = es[i] * us2f(kvb[((size_t)(b * T_ + t)) * 2048 + h * 128 + 64 + nt * 16 + col]);
    }

  const int nb = (qt * 32 + 94) >> 6;   // 64-key chunks, block-uniform
  for (int blk = 0; blk < nb; ++blk) {
    const int jb = blk * 64;
    __syncthreads();
    {
      // K tile: 12KB contiguous (pre-swizzled in global), linear async stage
      const u16* gk = KcH + (size_t)jb * 96 + (wid * 3) * 512 + lane * 8;
      u16* lk = &Ks[(wid * 3) * 512];
#pragma unroll
      for (int k = 0; k < 3; ++k)
        gload_lds16(gk + k * 512, lk + k * 512);
      // V tile: 64 dims x 64 keys, reg-staged into padded rows
      int d = tid >> 2, c4 = tid & 3;
      const u16* gv = VtH + (size_t)d * 1024 + jb + c4 * 16;
      u16* lv = &Vs[d][c4 * 16];
      *(u16x8*)(lv)     = *(const u16x8*)(gv);
      *(u16x8*)(lv + 8) = *(const u16x8*)(gv + 8);
    }
    __syncthreads();
#pragma unroll
    for (int cc = 0; cc < 2; ++cc){
      const u16* k0 = &Ks[(cc * 32 + col) * 96];
      const u16* k1 = k0 + 16 * 96;
      f32x4 s0 = {0,0,0,0}, s1 = {0,0,0,0};
      s0 = mfma32(aq0, ld8(k0 + qo), s0);
      s0 = mfma32(aq1, ld8(k0 + 32 + qo), s0);
      s0 = mfma32(aq2, ld8(k0 + 64 + qo), s0);
      s1 = mfma32(aq0, ld8(k1 + qo), s1);
      s1 = mfma32(aq1, ld8(k1 + 32 + qo), s1);
      s1 = mfma32(aq2, ld8(k1 + 64 + qo), s1);
      int key0 = jb + cc * 32 + col;
#pragma unroll
      for (int i = 0; i < 4; ++i){
        int lim = (t0 + quad * 4 + i) >> 1;
        float p0 = (key0 < lim)      ? __expf(s0[i] * scale) : 0.f;
        float p1 = (key0 + 16 < lim) ? __expf(s1[i] * scale) : 0.f;
        lacc[i] += p0 + p1;
        pbuf[(quad * 4 + i) * 72 + cc * 32 + col]      = f2us(p0);
        pbuf[(quad * 4 + i) * 72 + cc * 32 + 16 + col] = f2us(p1);
      }
    }
    asm volatile("s_waitcnt lgkmcnt(0)" ::: "memory");
    __builtin_amdgcn_sched_barrier(0);
#pragma unroll
    for (int cc = 0; cc < 2; ++cc){
      s16x8 pf = ld8(&pbuf[col * 72 + cc * 32 + quad * 8]);
#pragma unroll
      for (int nt = 0; nt < 4; ++nt)
        O[nt] = mfma32(pf, ld8(&Vs[nt * 16 + col][cc * 32 + quad * 8]), O[nt]);
    }
  }
#pragma unroll
  for (int i = 0; i < 4; ++i){
    float l = lacc[i];
    l += __shfl_xor(l, 1);
    l += __shfl_xor(l, 2);
    l += __shfl_xor(l, 4);
    l += __shfl_xor(l, 8);
    lacc[i] = es[i] + l;
  }
#pragma unroll
  for (int nt = 0; nt < 4; ++nt)
#pragma unroll
    for (int i = 0; i < 4; ++i){
      int t = t0 + quad * 4 + i;
      xout[((size_t)(b * T_ + t)) * 1024 + h * 64 + nt * 16 + col] = f2us(O[nt][i] / lacc[i]);
    }
}

extern "C" void kernel_launch(void* const* d_in, const int* in_sizes, int n_in,
                              void* d_out, int out_size, void* d_ws, size_t ws_size,
                              hipStream_t stream)
{
  (void)in_sizes; (void)n_in; (void)out_size; (void)ws_size;
  const float* query = (const float*)d_in[0];
  const float* key_  = (const float*)d_in[1];
  const int*   pos   = (const int*)d_in[3];
  const float* wq    = (const float*)d_in[4];
  const float* wkva  = (const float*)d_in[5];
  const float* gamma = (const float*)d_in[6];
  const float* beta  = (const float*)d_in[7];
  const float* wkvb  = (const float*)d_in[8];
  const float* wo    = (const float*)d_in[9];
  const float* fccw  = (const float*)d_in[10];
  const float* fccb  = (const float*)d_in[11];
  const float* fcpw  = (const float*)d_in[12];
  const float* fcpb  = (const float*)d_in[13];

  char* p = (char*)d_ws;
  auto alloc = [&](size_t bytes) -> void* {
    void* r = (void*)p;
    p += (bytes + 255) & ~(size_t)255;
    return r;
  };
  u16* wqT    = (u16*)alloc(1536ull * 2048 * 2);
  u16* wkvaT  = (u16*)alloc(288ull  * 2048 * 2);
  u16* woT    = (u16*)alloc(2048ull * 1024 * 2);
  u16* wkvbB  = (u16*)alloc(2048ull * 256 * 2);
  u16* queryB = (u16*)alloc(4096ull * 2048 * 2);
  u16* keyB   = (u16*)alloc(4096ull * 2048 * 2);
  u16* qp     = (u16*)alloc(2ull * 4096 * 1536 * 2);  // 2 split-K partials (25.2MB)
  float* kvp  = (float*)alloc(4ull * 4096 * 288 * 4); // 4 f32 key-proj partials (18.9MB)
  u16* qh     = (u16*)alloc(65536ull * 96 * 2);    // (B,H,T,96)
  u16* kvn    = (u16*)alloc(4096ull * 256 * 2);
  u16* kpe    = (u16*)alloc(4096ull * 32 * 2);
  float* P2   = (float*)alloc(4096ull * 64 * 4);
  float* C2   = (float*)alloc(2048ull * 64 * 4);
  u16* kvt    = (u16*)alloc(4096ull * 256 * 2);
  u16* kvb    = (u16*)alloc(4096ull * 2048 * 2);   // per-head [k_abs(64)|v(64)]
  // qp is dead after mid3; Kc/Vt/x are born at vtkc/attn -> alias onto qp
  char* q8 = (char*)qp;
  u16* Kc = (u16*)q8;                                    // 6.29MB (B,H,1024,96)
  u16* Vt = (u16*)(q8 + ((32ull*1024*96*2 + 255) & ~255ull));      // 4.19MB
  u16* x  = (u16*)(q8 + ((32ull*1024*96*2 + 255) & ~255ull)
                      + ((2048ull*1024*2   + 255) & ~255ull));     // 8.39MB

  prep_cvt<<<22592, 256, 0, stream>>>(wq, wkva, wo, wkvb, query, key_,
                                      wqT, wkvaT, woT, wkvbB, queryB, keyB);
  proj2<<<2048, 256, 0, stream>>>(queryB, wqT, qp, keyB, wkvaT, kvp);
  mid3<<<9216, 256, 0, stream>>>(qp, pos, qh, kvp, gamma, beta, fcpw, fcpb,
                                 kvn, P2, kpe, fccw, fccb, C2);
  kvt_kernel<<<1024, 256, 0, stream>>>(C2, P2, kvn, kvt);

  gemm128<0><<<512, 256, 0, stream>>>(kvt, wkvbB, kvb, 4096, 2048, 256, 16);
  vtkc_kernel<<<2048, 256, 0, stream>>>(kvb, kpe, Vt, Kc);
  attn_kernel<<<1024, 256, 0, stream>>>(qh, kvb, kpe, Kc, Vt, x);

  gemm128<1><<<512, 256, 0, stream>>>(x, woT, d_out, 4096, 2048, 1024, 16);
}

// Round 10
// 329.080 us; speedup vs baseline: 1.0360x; 1.0088x over previous
//
#include <hip/hip_runtime.h>
#include <stddef.h>

typedef unsigned short u16;
typedef unsigned short u16x8 __attribute__((ext_vector_type(8)));
typedef unsigned short u16x4 __attribute__((ext_vector_type(4)));
typedef short s16x8 __attribute__((ext_vector_type(8)));
typedef float f32x4 __attribute__((ext_vector_type(4)));

#define B_ 2
#define T_ 2048
#define E_ 2048
#define H_ 16

__device__ inline float us2f(u16 u){
  unsigned int i = ((unsigned int)u) << 16;
  return __builtin_bit_cast(float, i);
}
__device__ inline u16 f2us(float f){
  unsigned int x = __builtin_bit_cast(unsigned int, f);
  unsigned int r = (x + 0x7fffu + ((x >> 16) & 1u)) >> 16;
  return (u16)r;
}
__device__ inline f32x4 mfma32(s16x8 a, s16x8 b, f32x4 c){
  return __builtin_amdgcn_mfma_f32_16x16x32_bf16(a, b, c, 0, 0, 0);
}
__device__ inline s16x8 ld8(const u16* p){
  return __builtin_bit_cast(s16x8, *(const u16x8*)p);
}
// async global->LDS, 16B per lane; LDS dest = wave-uniform base + lane*16 (m97/m104)
__device__ inline void gload_lds16(const u16* g, u16* l){
  __builtin_amdgcn_global_load_lds(
      (const __attribute__((address_space(1))) unsigned int*)(g),
      (__attribute__((address_space(3))) unsigned int*)(l), 16, 0, 0);
}

// ==== FUSED stage 1, round-13: weight prep + input cvt, VECTORIZED stores (G13) ====
// R9 audit: old version committed Common-mistake #2 — transpose epilogue did 32
// SCALAR u16 stores/thread, cvt paths 4 scalar stores/thread, qk-cvt grid was
// 16384 blocks of 4KB each.  Rewrite: u16x8 (16B) stores everywhere, 16 elems/
// thread for cvt, grid 22592 -> 9920.  All tile dims divide 32 exactly -> no
// bounds checks.  blocks [0,5696): transposes; [5696,5824): wkvb; [5824,9920): q/k.
__global__ __launch_bounds__(256) void prep_cvt(
    const float* __restrict__ wq, const float* __restrict__ wkva,
    const float* __restrict__ wo, const float* __restrict__ wkvb,
    const float* __restrict__ query, const float* __restrict__ key_,
    u16* __restrict__ wqT, u16* __restrict__ wkvaT, u16* __restrict__ woT,
    u16* __restrict__ wkvbB, u16* __restrict__ queryB, u16* __restrict__ keyB)
{
  __shared__ float tile[32][33];
  const int bid = blockIdx.x;
  const int tid = threadIdx.x;
  if (bid < 5696) {
    const float* in; u16* out; int R, C, bx, by;
    if (bid < 3072)      { in = wq;   out = wqT;   R = 2048; C = 1536; bx = bid % 48;          by = bid / 48; }
    else if (bid < 3648) { in = wkva; out = wkvaT; R = 2048; C = 288;  bx = (bid-3072) % 9;    by = (bid-3072) / 9; }
    else                 { in = wo;   out = woT;   R = 1024; C = 2048; bx = (bid-3648) % 64;   by = (bid-3648) / 64; }
    int tx = tid & 31, ty = tid >> 5;   // 32 x 8
    int c0 = bx * 32, r0 = by * 32;
    for (int i = ty; i < 32; i += 8)
      tile[i][tx] = in[(size_t)(r0 + i) * C + c0 + tx];
    __syncthreads();
    if (tid < 128){                     // 16B vector stores: col c, 8 rows each
      int c = tid >> 2, rs = (tid & 3) * 8;
      u16x8 o;
#pragma unroll
      for (int k = 0; k < 8; ++k) o[k] = f2us(tile[rs + k][c]);
      *(u16x8*)(out + (size_t)(c0 + c) * R + r0 + rs) = o;
    }
  } else if (bid < 5824) {
    int i = ((bid - 5696) * 256 + tid) * 16;   // 128 blocks x 4096 elems = 2048*256
    f32x4 v0 = *(const f32x4*)(wkvb + i);
    f32x4 v1 = *(const f32x4*)(wkvb + i + 4);
    f32x4 v2 = *(const f32x4*)(wkvb + i + 8);
    f32x4 v3 = *(const f32x4*)(wkvb + i + 12);
    u16x8 o0, o1;
#pragma unroll
    for (int k = 0; k < 4; ++k){
      o0[k] = f2us(v0[k]); o0[k+4] = f2us(v1[k]);
      o1[k] = f2us(v2[k]); o1[k+4] = f2us(v3[k]);
    }
    *(u16x8*)(wkvbB + i)     = o0;
    *(u16x8*)(wkvbB + i + 8) = o1;
  } else {
    const int n_each = 4096 * 2048;
    int gi = ((bid - 5824) * 256 + tid) * 16;  // 4096 blocks x 4096 elems = 2 x 8.4M
    const float* in; u16* out; int i;
    if (gi < n_each){ in = query; out = queryB; i = gi; }
    else            { in = key_;  out = keyB;   i = gi - n_each; }
    f32x4 v0 = *(const f32x4*)(in + i);
    f32x4 v1 = *(const f32x4*)(in + i + 4);
    f32x4 v2 = *(const f32x4*)(in + i + 8);
    f32x4 v3 = *(const f32x4*)(in + i + 12);
    u16x8 o0, o1;
#pragma unroll
    for (int k = 0; k < 4; ++k){
      o0[k] = f2us(v0[k]); o0[k+4] = f2us(v1[k]);
      o1[k] = f2us(v2[k]); o1[k+4] = f2us(v3[k]);
    }
    *(u16x8*)(out + i)     = o0;
    *(u16x8*)(out + i + 8) = o1;
  }
}

// ==== FUSED stage 2, round-12: INTERLEAVED q-proj U key-proj, DEPTH-2 PIPELINE ====
// (unchanged from R9)  Roles interleaved 3:5 in bid-space; per-XCD contiguous ids.
// sk: split-K=2, 3-buffer depth-2 counted vmcnt(4).  bt: split-K=4 reg-prefetch,
// f32 partials kvp[4] summed in mid3's LN.
__global__ __launch_bounds__(256) void proj2(
    const u16* __restrict__ queryB, const u16* __restrict__ wqT, u16* __restrict__ qp,
    const u16* __restrict__ keyB, const u16* __restrict__ wkvaT, float* __restrict__ kvp)
{
  __shared__ __align__(16) u16 smem[24576];   // sk: As[0..12288) Bs[12288..24576); bt: 5120 used
  const int bid = blockIdx.x;
  const int tid  = threadIdx.x;
  const int lane = tid & 63;
  const int wid  = tid >> 6;
  const int quad = lane >> 4;
  const int col  = lane & 15;
  const int g  = bid >> 3;
  const int e  = bid & 7;      // XCD (round-robin assumption)
  const int gm = g & 7;

  if (gm < 3) {
    // ---- sk: split-K=2 3-buffer 128x128 GEMM: M=4096 N=1536 K=2048 Klen=1024 ----
    const int id = e * 96 + (g >> 3) * 3 + gm;     // 0..767, per-XCD contiguous
    const int kh   = id / 384;
    const int r2   = id % 384;
    const int bmHi = r2 / 48;
    const int r3   = r2 % 48;
    const int bn = (r3 >> 2) * 128;
    const int bm = (bmHi * 4 + (r3 & 3)) * 128;
    const int N = 1536, K = 2048, Klen = 1024;
    const int waveM = wid >> 1, waveN = wid & 1;
    u16* As = smem;
    u16* Bs = smem + 12288;

    const int srow = wid * 16 + (lane >> 2);
    const int scol = (lane & 3) * 8;
    const u16* ga = queryB + (size_t)(bm + srow) * K + kh * Klen + scol;
    const u16* gb = wqT    + (size_t)(bn + srow) * K + kh * Klen + scol;
    const size_t rowskip = (size_t)64 * K;
    u16* Cp = qp + (size_t)kh * 4096 * N;

    f32x4 acc[4][4] = {};
    const int nt = Klen >> 5;   // 32

    auto STAGE = [&](int buf, int kk){
      u16* la = &As[buf * 4096 + wid * 512];
      u16* lb = &Bs[buf * 4096 + wid * 512];
      gload_lds16(ga + kk,           la);
      gload_lds16(ga + rowskip + kk, la + 2048);
      gload_lds16(gb + kk,           lb);
      gload_lds16(gb + rowskip + kk, lb + 2048);
    };

    STAGE(0, 0);
    STAGE(1, 32);
    asm volatile("s_waitcnt vmcnt(4)" ::: "memory");   // tile 0 landed; tile 1 in flight
    __builtin_amdgcn_s_barrier();
    __builtin_amdgcn_sched_barrier(0);

    int bc = 0;
    for (int it = 0; it < nt; ++it){
      if (it + 2 < nt){
        int bs = bc + 2; if (bs >= 3) bs -= 3;
        STAGE(bs, (it + 2) * 32);
      }
      const u16* as = &As[bc * 4096];
      const u16* bs_ = &Bs[bc * 4096];
      s16x8 af[4], bf[4];
#pragma unroll
      for (int i = 0; i < 4; ++i) af[i] = ld8(&as[(waveM*64 + i*16 + col) * 32 + quad*8]);
#pragma unroll
      for (int i = 0; i < 4; ++i) bf[i] = ld8(&bs_[(waveN*64 + i*16 + col) * 32 + quad*8]);
      __builtin_amdgcn_s_setprio(1);
#pragma unroll
      for (int i = 0; i < 4; ++i)
#pragma unroll
        for (int j = 0; j < 4; ++j)
          acc[i][j] = mfma32(af[i], bf[j], acc[i][j]);
      __builtin_amdgcn_s_setprio(0);
      asm volatile("s_waitcnt lgkmcnt(0)" ::: "memory");
      if (it + 2 < nt)
        asm volatile("s_waitcnt vmcnt(4)" ::: "memory");   // next tile drained; newest stays in flight
      else
        asm volatile("s_waitcnt vmcnt(0)" ::: "memory");
      __builtin_amdgcn_s_barrier();
      __builtin_amdgcn_sched_barrier(0);
      bc += 1; if (bc == 3) bc = 0;
    }
#pragma unroll
    for (int i = 0; i < 4; ++i)
#pragma unroll
      for (int j = 0; j < 4; ++j)
#pragma unroll
        for (int r = 0; r < 4; ++r) {
          int row = bm + waveM*64 + i*16 + quad*4 + r;
          int c   = bn + waveN*64 + j*16 + col;
          Cp[(size_t)row * N + c] = f2us(acc[i][j][r]);
        }
  } else {
    // ---- bt: split-K=4 reg-prefetch 64x64 GEMM: kvp[kh] = keyB@wkvaT^T slice ----
    const int id = e * 160 + (g >> 3) * 5 + (gm - 3);   // 0..1279, per-XCD contiguous
    const int kh = id / 320;
    const int r  = id % 320;
    const int bm = (r / 5) * 64;
    const int bn = (r % 5) * 64;
    const int N = 288, K = 2048, Klen = 512;
    const int lr = tid >> 2;
    const int lc = (tid & 3) * 8;
    const int waveM = wid >> 1, waveN = wid & 1;
    u16* As = smem;                    // [64][40] padded (conflict-free ds_read)
    u16* Bs = smem + 2560;

    f32x4 acc[2][2];
    for (int i = 0; i < 2; ++i)
      for (int j = 0; j < 2; ++j)
        acc[i][j] = (f32x4){0.f, 0.f, 0.f, 0.f};

    const u16x8 zero8 = {0,0,0,0,0,0,0,0};
    const bool bok = (bn + lr) < N;
    const u16* arow = keyB  + (size_t)(bm + lr) * K + kh * Klen + lc;
    const u16* brow = wkvaT + (size_t)(bn + lr) * K + kh * Klen + lc;
    float* Cp = kvp + (size_t)kh * 4096 * N;

    u16x8 av = *(const u16x8*)(arow);
    u16x8 bv = bok ? *(const u16x8*)(brow) : zero8;
    for (int kk = 0; kk < Klen; kk += 32) {
      __syncthreads();
      *(u16x8*)&As[lr*40 + lc] = av;
      *(u16x8*)&Bs[lr*40 + lc] = bv;
      if (kk + 32 < Klen){                       // issue next-step loads now;
        av = *(const u16x8*)(arow + kk + 32);    // ds_read+MFMA below covers latency
        bv = bok ? *(const u16x8*)(brow + kk + 32) : zero8;
      }
      __syncthreads();
      s16x8 af0 = ld8(&As[(waveM*32 + col)*40 + quad*8]);
      s16x8 af1 = ld8(&As[(waveM*32 + 16 + col)*40 + quad*8]);
      s16x8 bf0 = ld8(&Bs[(waveN*32 + col)*40 + quad*8]);
      s16x8 bf1 = ld8(&Bs[(waveN*32 + 16 + col)*40 + quad*8]);
      acc[0][0] = mfma32(af0, bf0, acc[0][0]);
      acc[0][1] = mfma32(af0, bf1, acc[0][1]);
      acc[1][0] = mfma32(af1, bf0, acc[1][0]);
      acc[1][1] = mfma32(af1, bf1, acc[1][1]);
    }
    for (int am = 0; am < 2; ++am)
      for (int bnn = 0; bnn < 2; ++bnn)
        for (int i = 0; i < 4; ++i) {
          int rr = bm + waveM*32 + am*16 + quad*4 + i;
          int c  = bn + waveN*32 + bnn*16 + col;
          if (c < N) Cp[(size_t)rr * N + c] = acc[am][bnn][i];
        }
  }
}

// ------- 3-buffer depth-2 128x128 GEMM (T4 counted-vmcnt, XCD-swizzled) -------
// STAGE(tile it+2) at top; vmcnt(4) at bottom keeps the newest 4 loads in flight
// across the barrier (drains only tile it+1).  48KB LDS.
template<int OUT_F32>
__global__ __launch_bounds__(256) void gemm128(const u16* __restrict__ A,
    const u16* __restrict__ Bt, void* __restrict__ Cp, int M, int N, int K, int gx)
{
  __shared__ __align__(16) u16 As[3 * 128 * 32];
  __shared__ __align__(16) u16 Bs[3 * 128 * 32];
  const int lin = blockIdx.x;
  const int cpx = gridDim.x >> 3;
  const int swz = (lin & 7) * cpx + (lin >> 3);
  const int bxi = swz % gx;
  const int byi = swz / gx;
  const int tid  = threadIdx.x;
  const int lane = tid & 63;
  const int wid  = tid >> 6;
  const int quad = lane >> 4;
  const int col  = lane & 15;
  const int bm = byi * 128;
  const int bn = bxi * 128;
  const int waveM = wid >> 1, waveN = wid & 1;

  const int srow = wid * 16 + (lane >> 2);
  const int scol = (lane & 3) * 8;
  const u16* ga = A  + (size_t)(bm + srow) * K + scol;
  const u16* gb = Bt + (size_t)(bn + srow) * K + scol;
  const size_t rowskip = (size_t)64 * K;

  f32x4 acc[4][4] = {};
  const int nt = K >> 5;

  auto STAGE = [&](int buf, int kk){
    u16* la = &As[buf * 4096 + wid * 512];
    u16* lb = &Bs[buf * 4096 + wid * 512];
    gload_lds16(ga + kk,           la);
    gload_lds16(ga + rowskip + kk, la + 2048);
    gload_lds16(gb + kk,           lb);
    gload_lds16(gb + rowskip + kk, lb + 2048);
  };

  STAGE(0, 0);
  if (nt > 1){
    STAGE(1, 32);
    asm volatile("s_waitcnt vmcnt(4)" ::: "memory");   // tile 0 landed
  } else {
    asm volatile("s_waitcnt vmcnt(0)" ::: "memory");
  }
  __builtin_amdgcn_s_barrier();
  __builtin_amdgcn_sched_barrier(0);

  int bc = 0;
  for (int it = 0; it < nt; ++it){
    if (it + 2 < nt){
      int bs = bc + 2; if (bs >= 3) bs -= 3;
      STAGE(bs, (it + 2) * 32);
    }
    const u16* as = &As[bc * 4096];
    const u16* bs_ = &Bs[bc * 4096];
    s16x8 af[4], bf[4];
#pragma unroll
    for (int i = 0; i < 4; ++i) af[i] = ld8(&as[(waveM*64 + i*16 + col) * 32 + quad*8]);
#pragma unroll
    for (int i = 0; i < 4; ++i) bf[i] = ld8(&bs_[(waveN*64 + i*16 + col) * 32 + quad*8]);
#pragma unroll
    for (int i = 0; i < 4; ++i)
#pragma unroll
      for (int j = 0; j < 4; ++j)
        acc[i][j] = mfma32(af[i], bf[j], acc[i][j]);
    asm volatile("s_waitcnt lgkmcnt(0)" ::: "memory");
    if (it + 2 < nt)
      asm volatile("s_waitcnt vmcnt(4)" ::: "memory");
    else
      asm volatile("s_waitcnt vmcnt(0)" ::: "memory");
    __builtin_amdgcn_s_barrier();
    __builtin_amdgcn_sched_barrier(0);
    bc += 1; if (bc == 3) bc = 0;
  }
#pragma unroll
  for (int i = 0; i < 4; ++i)
#pragma unroll
    for (int j = 0; j < 4; ++j)
#pragma unroll
      for (int r = 0; r < 4; ++r) {
        int row = bm + waveM*64 + i*16 + quad*4 + r;
        int c   = bn + waveN*64 + j*16 + col;
        if (OUT_F32) ((float*)Cp)[(size_t)row * N + c] = acc[i][j][r];
        else         ((u16*)Cp)[(size_t)row * N + c]   = f2us(acc[i][j][r]);
      }
}

// ==== FUSED stage 3: qsplit (2 bf16 partials) U ln_p2_rope (4 f32 kvp partials) U c2 ====
// blocks [0,3072): qsplit; [3072,7168): ln_p2_rope; [7168,9216): c2
__global__ __launch_bounds__(256) void mid3(
    const u16* __restrict__ qp, const int* __restrict__ pos, u16* __restrict__ qh,
    const float* __restrict__ kvp, const float* __restrict__ gamma,
    const float* __restrict__ beta, const float* __restrict__ fcpw,
    const float* __restrict__ fcpb, u16* __restrict__ kvn,
    float* __restrict__ P2, u16* __restrict__ kpe,
    const float* __restrict__ fccw, const float* __restrict__ fccb,
    float* __restrict__ C2)
{
  __shared__ float fsm[520];    // ln: kvs[256]+part[256]+redS[4]+redS2[4]; c2: pe+part
  const int bid = blockIdx.x;
  const int tid = threadIdx.x;

  if (bid < 3072) {
    // ---- qsplit: combine 2 split-K partials + rope dims 64..95 ----
    const size_t PS = 4096ull * 1536;
    int idx = bid * 256 + tid;
    int c    = idx % 12;
    int rest = idx / 12;
    int h    = rest & 15;
    int row  = rest >> 4;
    int t    = row & (T_ - 1);
    int b    = row >> 11;
    size_t off = (size_t)row * 1536 + h * 96 + c * 8;
    u16x8 v0 = *(const u16x8*)(qp + off);
    u16x8 v1 = *(const u16x8*)(qp + PS + off);
    u16x8 v;
    if (c < 8) {
#pragma unroll
      for (int k = 0; k < 8; ++k) v[k] = f2us(us2f(v0[k]) + us2f(v1[k]));
    } else {
      int i0 = (c - 8) * 4;
      float pp = (float)pos[t];
#pragma unroll
      for (int k = 0; k < 4; ++k){
        int i = i0 + k;
        float ang = pp * __expf((float)(2*i) * -0.28782313657f); // -ln(1e4)/32
        float cs = __cosf(ang), sn = __sinf(ang);
        float xr = us2f(v0[2*k])   + us2f(v1[2*k]);
        float xi = us2f(v0[2*k+1]) + us2f(v1[2*k+1]);
        v[2*k]   = f2us(xr * cs - xi * sn);
        v[2*k+1] = f2us(xr * sn + xi * cs);
      }
    }
    u16* dst = qh + ((size_t)(b * 16 + h) * T_ + t) * 96;
    *(u16x8*)(dst + c * 8) = v;
  } else if (bid < 7168) {
    // ---- layernorm(sum of 4 kvp partials) + P2 + rope(k_pe) ----
    const int row = bid - 3072;
    const int lane = tid & 63, wid = tid >> 6;
    const size_t PSk = 4096ull * 288;
    float* kvs   = fsm;
    float* part  = fsm + 256;
    float* redS  = fsm + 512;
    float* redS2 = fsm + 516;
    const float* src = kvp + (size_t)row * 288;
    float v = (src[tid] + src[PSk + tid]) + (src[2*PSk + tid] + src[3*PSk + tid]);
    float s1 = v, s2 = v * v;
    for (int off = 1; off < 64; off <<= 1){
      s1 += __shfl_xor(s1, off);
      s2 += __shfl_xor(s2, off);
    }
    if (lane == 0){ redS[wid] = s1; redS2[wid] = s2; }
    __syncthreads();
    float S  = redS[0] + redS[1] + redS[2] + redS[3];
    float Q  = redS2[0] + redS2[1] + redS2[2] + redS2[3];
    float mean = S * (1.f / 256.f);
    float var  = Q * (1.f / 256.f) - mean * mean;
    float rstd = rsqrtf(var + 1e-5f);
    float xn = (v - mean) * rstd * gamma[tid] + beta[tid];
    kvs[tid] = xn;
    kvn[(size_t)row * 256 + tid] = f2us(xn);
    __syncthreads();
    {
      int oc = tid & 63, pp = tid >> 6;
      float acc = 0.f;
#pragma unroll 8
      for (int c = pp * 64; c < pp * 64 + 64; ++c)
        acc += kvs[c] * fcpw[c * 64 + oc];
      part[tid] = acc;
    }
    __syncthreads();
    if (tid < 64) {
      P2[(size_t)row * 64 + tid] = fcpb[tid] + part[tid] + part[64 + tid]
                                 + part[128 + tid] + part[192 + tid];
    } else if (tid < 80) {
      int i = tid - 64;
      int t = row & (T_ - 1);
      float ang = (float)pos[t] * __expf((float)(2*i) * -0.28782313657f);
      float c = __cosf(ang), s = __sinf(ang);
      float xr = (src[256 + 2*i] + src[PSk + 256 + 2*i])
               + (src[2*PSk + 256 + 2*i] + src[3*PSk + 256 + 2*i]);
      float xi = (src[257 + 2*i] + src[PSk + 257 + 2*i])
               + (src[2*PSk + 257 + 2*i] + src[3*PSk + 257 + 2*i]);
      kpe[(size_t)row * 32 + 2*i]     = f2us(xr * c - xi * s);
      kpe[(size_t)row * 32 + 2*i + 1] = f2us(xr * s + xi * c);
    }
  } else {
    // ---- C2[t] = sinusoid_pe(t/2) @ fc_c_w + b ----
    const int t = bid - 7168;
    float* pe   = fsm;
    float* part = fsm + 256;
    float p = (float)(t >> 1);
    if (tid < 128){
      float div = __expf((float)(2*tid) * -0.03597789207f);  // -ln(1e4)/256
      float a = p * div;
      pe[2*tid]   = __sinf(a);
      pe[2*tid+1] = __cosf(a);
    }
    __syncthreads();
    {
      int oc = tid & 63, pp = tid >> 6;
      float acc = 0.f;
#pragma unroll 8
      for (int c = pp * 64; c < pp * 64 + 64; ++c)
        acc += pe[c] * fccw[c * 64 + oc];
      part[tid] = acc;
    }
    __syncthreads();
    if (tid < 64)
      C2[t * 64 + tid] = fccb[tid] + part[tid] + part[64 + tid]
                       + part[128 + tid] + part[192 + tid];
  }
}

// ---------------- kv_t: block-diag (DR=2) temporal conv; 4 rows/block --------
// Round-13: u16x4 vector loads/stores (was 4x scalar u16).
__global__ __launch_bounds__(256) void kvt_kernel(const float* __restrict__ C2,
    const float* __restrict__ P2, const u16* __restrict__ kvn, u16* __restrict__ kvt)
{
  const int row = blockIdx.x * 4 + (threadIdx.x >> 6);   // 1024 blocks x 4 waves
  const int lane = threadIdx.x & 63;
  const int t = row & (T_ - 1);
  float c2v = C2[t * 64 + lane];
  float da = c2v * P2[(size_t)row * 64 + lane];
  for (int off = 1; off < 64; off <<= 1) da += __shfl_xor(da, off);
  float wtt = 1.f / (1.f + __expf(-da));
  const bool odd = (t & 1);
  float wts = 0.f;
  if (odd){
    float db = c2v * P2[(size_t)(row - 1) * 64 + lane];
    for (int off = 1; off < 64; off <<= 1) db += __shfl_xor(db, off);
    wts = 1.f / (1.f + __expf(-db));
  }
  u16x4 a = *(const u16x4*)(kvn + (size_t)row * 256 + lane * 4);
  u16x4 o;
  if (odd){
    u16x4 pvv = *(const u16x4*)(kvn + (size_t)(row - 1) * 256 + lane * 4);
#pragma unroll
    for (int k = 0; k < 4; ++k)
      o[k] = f2us(wtt * us2f(a[k]) + wts * us2f(pvv[k]));
  } else {
#pragma unroll
    for (int k = 0; k < 4; ++k)
      o[k] = f2us(wtt * us2f(a[k]));
  }
  *(u16x4*)(kvt + (size_t)row * 256 + lane * 4) = o;
}

// ---- fused: Vt transpose-gather (blocks 0..511) + Kc gather (blocks 512..2047) ----
// Kc is stored XOR-SWIZZLED within each 64-key tile: logical 16B chunk c (0..11)
// of local key kl lands at c' = (c&12) | ((c&3) ^ ((kl>>1)&3)).  attn_kernel
// stages tiles linearly via global_load_lds and applies the same XOR on ds_read,
// making the QK B-operand reads LDS bank-conflict-free (was 4-way).
__global__ __launch_bounds__(256) void vtkc_kernel(const u16* __restrict__ kvb,
    const u16* __restrict__ kpe, u16* __restrict__ Vt, u16* __restrict__ Kc)
{
  __shared__ __align__(16) u16 tile[64][72];
  const int tid = threadIdx.x;
  if (blockIdx.x < 512) {
    const int bid = blockIdx.x;
    const int jt = bid & 15;
    const int h  = (bid >> 4) & 15;
    const int b  = bid >> 8;
    const int jl = tid >> 2;
    const int dseg = (tid & 3) * 16;
    const int j0 = jt * 64;
    {
      int s_ = 2 * (j0 + jl) + 1;
      const u16* src = kvb + ((size_t)(b * T_ + s_)) * 2048 + h * 128 + 64 + dseg;
      *(u16x8*)&tile[jl][dseg]     = *(const u16x8*)(src);
      *(u16x8*)&tile[jl][dseg + 8] = *(const u16x8*)(src + 8);
    }
    __syncthreads();
    const int dl = tid >> 2;
    const int jseg = (tid & 3) * 16;
    u16* dst = Vt + ((size_t)(b * 16 + h) * 64 + dl) * 1024 + j0 + jseg;
    u16x8 o;
    for (int r = 0; r < 8; ++r) o[r] = tile[jseg + r][dl];
    *(u16x8*)dst = o;
    for (int r = 0; r < 8; ++r) o[r] = tile[jseg + 8 + r][dl];
    *(u16x8*)(dst + 8) = o;
  } else {
    int idx = (blockIdx.x - 512) * 256 + tid;   // 1536 blocks x 256 chunks
    int c  = idx % 12;
    int j  = (idx / 12) & 1023;
    int bh = idx / (12 * 1024);
    if (bh >= B_ * H_) return;
    int b = bh >> 4, h = bh & 15;
    int t = 2 * j + 1;
    u16x8 v;
    if (c < 8) v = *(const u16x8*)(kvb + ((size_t)(b * T_ + t)) * 2048 + h * 128 + c * 8);
    else       v = *(const u16x8*)(kpe + ((size_t)(b * T_ + t)) * 32 + (c - 8) * 8);
    int kl = j & 63;                              // local key within 64-key tile
    int cs = (c & 12) | ((c & 3) ^ ((kl >> 1) & 3));   // swizzled chunk slot
    *(u16x8*)(Kc + ((size_t)bh * 1024 + j) * 96 + cs * 8) = v;
  }
}

// ---- flash attention: fixed-max softmax, 64-key LDS chunks, one q-tile/block ----
// 1024 blocks (one qt each, big-qt first), 30KB LDS -> 16 waves/CU.
// Ks reads XOR-deswizzled (conflict-free).  Round-13: + T5 setprio around MFMA
// clusters (attn has multi-block role diversity; m191: +4-7%).
__global__ __launch_bounds__(256) void attn_kernel(
    const u16* __restrict__ qh, const u16* __restrict__ kvb,
    const u16* __restrict__ kpe, const u16* __restrict__ Kc,
    const u16* __restrict__ Vt, u16* __restrict__ xout)
{
  __shared__ __align__(16) u16 Ks[64 * 96];        // 64 keys x 96 dims, swizzled
  __shared__ __align__(16) u16 Vs[64][72];         // 64 dims x 64 keys (+8 pad)
  __shared__ __align__(16) u16 pbufA[4][16 * 72];  // per-wave P: 16 q x 64 keys
  const int tid  = threadIdx.x;
  const int wid  = tid >> 6;
  const int lane = tid & 63;
  const int quad = lane >> 4;
  const int col  = lane & 15;
  const int qt   = 31 - (blockIdx.x >> 5);   // big q-tiles dispatched first
  const int bh   = blockIdx.x & 31;
  const int b    = bh >> 4;
  const int h    = bh & 15;
  u16* pbuf = pbufA[wid];
  const float scale = 0.10206207262f;   // 96^-0.5
  const u16* KcH = Kc + (size_t)bh * 1024 * 96;
  const u16* VtH = Vt + (size_t)bh * 64 * 1024;
  const int t0 = qt * 64 + wid * 16;
  const int qo = (quad * 8) ^ (((col >> 1) & 3) << 3);   // deswizzled read offset

  s16x8 aq0, aq1, aq2;
  {
    const u16* qrow = qh + ((size_t)bh * T_ + t0 + col) * 96;
    aq0 = ld8(qrow + quad * 8);
    aq1 = ld8(qrow + 32 + quad * 8);
    aq2 = ld8(qrow + 64 + quad * 8);
  }
  float sself;
  {
    const int t = t0 + col;
    const u16* qrow = qh + ((size_t)bh * T_ + t) * 96;
    const u16* ka = kvb + ((size_t)(b * T_ + t)) * 2048 + h * 128;
    const u16* kp = kpe + ((size_t)(b * T_ + t)) * 32;
    float a = 0.f;
#pragma unroll
    for (int c = 0; c < 8; ++c){
      u16x8 qv = *(const u16x8*)(qrow + c * 8);
      u16x8 kv = *(const u16x8*)(ka + c * 8);
#pragma unroll
      for (int jj = 0; jj < 8; ++jj) a += us2f(qv[jj]) * us2f(kv[jj]);
    }
#pragma unroll
    for (int c = 0; c < 4; ++c){
      u16x8 qv = *(const u16x8*)(qrow + 64 + c * 8);
      u16x8 kv = *(const u16x8*)(kp + c * 8);
#pragma unroll
      for (int jj = 0; jj < 8; ++jj) a += us2f(qv[jj]) * us2f(kv[jj]);
    }
    sself = a * scale;
  }
  float es[4], lacc[4];
  f32x4 O[4];
#pragma unroll
  for (int i = 0; i < 4; ++i){
    es[i] = __expf(__shfl(sself, quad * 4 + i));
    lacc[i] = 0.f;
  }
#pragma unroll
  for (int nt = 0; nt < 4; ++nt)
#pragma unroll
    for (int i = 0; i < 4; ++i){
      int t = t0 + quad * 4 + i;
      O[nt][i] = es[i] * us2f(kvb[((size_t)(b * T_ + t)) * 2048 + h * 128 + 64 + nt * 16 + col]);
    }

  const int nb = (qt * 32 + 94) >> 6;   // 64-key chunks, block-uniform
  for (int blk = 0; blk < nb; ++blk) {
    const int jb = blk * 64;
    __syncthreads();
    {
      // K tile: 12KB contiguous (pre-swizzled in global), linear async stage
      const u16* gk = KcH + (size_t)jb * 96 + (wid * 3) * 512 + lane * 8;
      u16* lk = &Ks[(wid * 3) * 512];
#pragma unroll
      for (int k = 0; k < 3; ++k)
        gload_lds16(gk + k * 512, lk + k * 512);
      // V tile: 64 dims x 64 keys, reg-staged into padded rows
      int d = tid >> 2, c4 = tid & 3;
      const u16* gv = VtH + (size_t)d * 1024 + jb + c4 * 16;
      u16* lv = &Vs[d][c4 * 16];
      *(u16x8*)(lv)     = *(const u16x8*)(gv);
      *(u16x8*)(lv + 8) = *(const u16x8*)(gv + 8);
    }
    __syncthreads();
#pragma unroll
    for (int cc = 0; cc < 2; ++cc){
      const u16* k0 = &Ks[(cc * 32 + col) * 96];
      const u16* k1 = k0 + 16 * 96;
      f32x4 s0 = {0,0,0,0}, s1 = {0,0,0,0};
      __builtin_amdgcn_s_setprio(1);
      s0 = mfma32(aq0, ld8(k0 + qo), s0);
      s0 = mfma32(aq1, ld8(k0 + 32 + qo), s0);
      s0 = mfma32(aq2, ld8(k0 + 64 + qo), s0);
      s1 = mfma32(aq0, ld8(k1 + qo), s1);
      s1 = mfma32(aq1, ld8(k1 + 32 + qo), s1);
      s1 = mfma32(aq2, ld8(k1 + 64 + qo), s1);
      __builtin_amdgcn_s_setprio(0);
      int key0 = jb + cc * 32 + col;
#pragma unroll
      for (int i = 0; i < 4; ++i){
        int lim = (t0 + quad * 4 + i) >> 1;
        float p0 = (key0 < lim)      ? __expf(s0[i] * scale) : 0.f;
        float p1 = (key0 + 16 < lim) ? __expf(s1[i] * scale) : 0.f;
        lacc[i] += p0 + p1;
        pbuf[(quad * 4 + i) * 72 + cc * 32 + col]      = f2us(p0);
        pbuf[(quad * 4 + i) * 72 + cc * 32 + 16 + col] = f2us(p1);
      }
    }
    asm volatile("s_waitcnt lgkmcnt(0)" ::: "memory");
    __builtin_amdgcn_sched_barrier(0);
    __builtin_amdgcn_s_setprio(1);
#pragma unroll
    for (int cc = 0; cc < 2; ++cc){
      s16x8 pf = ld8(&pbuf[col * 72 + cc * 32 + quad * 8]);
#pragma unroll
      for (int nt = 0; nt < 4; ++nt)
        O[nt] = mfma32(pf, ld8(&Vs[nt * 16 + col][cc * 32 + quad * 8]), O[nt]);
    }
    __builtin_amdgcn_s_setprio(0);
  }
#pragma unroll
  for (int i = 0; i < 4; ++i){
    float l = lacc[i];
    l += __shfl_xor(l, 1);
    l += __shfl_xor(l, 2);
    l += __shfl_xor(l, 4);
    l += __shfl_xor(l, 8);
    lacc[i] = es[i] + l;
  }
#pragma unroll
  for (int nt = 0; nt < 4; ++nt)
#pragma unroll
    for (int i = 0; i < 4; ++i){
      int t = t0 + quad * 4 + i;
      xout[((size_t)(b * T_ + t)) * 1024 + h * 64 + nt * 16 + col] = f2us(O[nt][i] / lacc[i]);
    }
}

extern "C" void kernel_launch(void* const* d_in, const int* in_sizes, int n_in,
                              void* d_out, int out_size, void* d_ws, size_t ws_size,
                              hipStream_t stream)
{
  (void)in_sizes; (void)n_in; (void)out_size; (void)ws_size;
  const float* query = (const float*)d_in[0];
  const float* key_  = (const float*)d_in[1];
  const int*   pos   = (const int*)d_in[3];
  const float* wq    = (const float*)d_in[4];
  const float* wkva  = (const float*)d_in[5];
  const float* gamma = (const float*)d_in[6];
  const float* beta  = (const float*)d_in[7];
  const float* wkvb  = (const float*)d_in[8];
  const float* wo    = (const float*)d_in[9];
  const float* fccw  = (const float*)d_in[10];
  const float* fccb  = (const float*)d_in[11];
  const float* fcpw  = (const float*)d_in[12];
  const float* fcpb  = (const float*)d_in[13];

  char* p = (char*)d_ws;
  auto alloc = [&](size_t bytes) -> void* {
    void* r = (void*)p;
    p += (bytes + 255) & ~(size_t)255;
    return r;
  };
  u16* wqT    = (u16*)alloc(1536ull * 2048 * 2);
  u16* wkvaT  = (u16*)alloc(288ull  * 2048 * 2);
  u16* woT    = (u16*)alloc(2048ull * 1024 * 2);
  u16* wkvbB  = (u16*)alloc(2048ull * 256 * 2);
  u16* queryB = (u16*)alloc(4096ull * 2048 * 2);
  u16* keyB   = (u16*)alloc(4096ull * 2048 * 2);
  u16* qp     = (u16*)alloc(2ull * 4096 * 1536 * 2);  // 2 split-K partials (25.2MB)
  float* kvp  = (float*)alloc(4ull * 4096 * 288 * 4); // 4 f32 key-proj partials (18.9MB)
  u16* qh     = (u16*)alloc(65536ull * 96 * 2);    // (B,H,T,96)
  u16* kvn    = (u16*)alloc(4096ull * 256 * 2);
  u16* kpe    = (u16*)alloc(4096ull * 32 * 2);
  float* P2   = (float*)alloc(4096ull * 64 * 4);
  float* C2   = (float*)alloc(2048ull * 64 * 4);
  u16* kvt    = (u16*)alloc(4096ull * 256 * 2);
  u16* kvb    = (u16*)alloc(4096ull * 2048 * 2);   // per-head [k_abs(64)|v(64)]
  // qp is dead after mid3; Kc/Vt/x are born at vtkc/attn -> alias onto qp
  char* q8 = (char*)qp;
  u16* Kc = (u16*)q8;                                    // 6.29MB (B,H,1024,96)
  u16* Vt = (u16*)(q8 + ((32ull*1024*96*2 + 255) & ~255ull));      // 4.19MB
  u16* x  = (u16*)(q8 + ((32ull*1024*96*2 + 255) & ~255ull)
                      + ((2048ull*1024*2   + 255) & ~255ull));     // 8.39MB

  prep_cvt<<<9920, 256, 0, stream>>>(wq, wkva, wo, wkvb, query, key_,
                                     wqT, wkvaT, woT, wkvbB, queryB, keyB);
  proj2<<<2048, 256, 0, stream>>>(queryB, wqT, qp, keyB, wkvaT, kvp);
  mid3<<<9216, 256, 0, stream>>>(qp, pos, qh, kvp, gamma, beta, fcpw, fcpb,
                                 kvn, P2, kpe, fccw, fccb, C2);
  kvt_kernel<<<1024, 256, 0, stream>>>(C2, P2, kvn, kvt);

  gemm128<0><<<512, 256, 0, stream>>>(kvt, wkvbB, kvb, 4096, 2048, 256, 16);
  vtkc_kernel<<<2048, 256, 0, stream>>>(kvb, kpe, Vt, Kc);
  attn_kernel<<<1024, 256, 0, stream>>>(qh, kvb, kpe, Kc, Vt, x);

  gemm128<1><<<512, 256, 0, stream>>>(x, woT, d_out, 4096, 2048, 1024, 16);
}